// Round 3
// baseline (843.974 us; speedup 1.0000x reference)
//
#include <hip/hip_runtime.h>
#include <cstdint>

typedef unsigned short u16;
typedef __attribute__((ext_vector_type(8))) _Float16 f16x8;
typedef __attribute__((ext_vector_type(4))) float f32x4;

#define SPLITN 7

__device__ __forceinline__ float b2f(u16 u) {
  union { unsigned int i; float f; } v; v.i = ((unsigned int)u) << 16; return v.f;
}
__device__ __forceinline__ u16 f2b(float f) {
  union { float f; unsigned int i; } v; v.f = f;
  unsigned int x = v.i;
  return (u16)((x + 0x7fffu + ((x >> 16) & 1u)) >> 16);
}
__device__ __forceinline__ u16 f2h(float f) {
  union { _Float16 h; u16 u; } v; v.h = (_Float16)f; return v.u;
}
__device__ __forceinline__ float h2f(u16 u) {
  union { u16 u; _Float16 h; } v; v.u = u; return (float)v.h;
}
// Flag-dispatched input load: f=1 -> float32 buffer, f=0 -> bf16 buffer.
__device__ __forceinline__ float ld(const void* p, long i, int f) {
  return f ? ((const float*)p)[i] : b2f(((const u16*)p)[i]);
}

// Kd: dtype sniffer — see theory. flag=1 means inputs/output are float32.
__global__ void detect_kernel(const u16* __restrict__ x, int* __restrict__ flag) {
  if (threadIdx.x == 0) {
    int bad = 0;
    for (int i = 0; i < 512; ++i) {
      const float v = fabsf(b2f(x[2 * i]));
      if (!(v < 100.f) || v < 1e-6f) ++bad;  // !(v<100) also catches NaN
    }
    *flag = (bad > 16) ? 1 : 0;
  }
}

// K0: weight [R][C] -> fp16 [C][R]
__global__ void transpose_cvt_kernel(const void* __restrict__ in, u16* __restrict__ out,
                                     int R, int C, const int* __restrict__ flagp) {
  const int f = *flagp;
  const int o = blockIdx.x * 256 + threadIdx.x;
  if (o < R * C) {
    const int i = o / R, j = o % R;
    out[o] = f2h(ld(in, (long)j * C + i, f));
  }
}

// K1: dwconv 3x3 + group cumsum + LayerNorm. One block per token.
__global__ __launch_bounds__(256) void dwconv_ln_kernel(
    const void* __restrict__ x, const void* __restrict__ dwk, const void* __restrict__ dwb,
    const void* __restrict__ lng, const void* __restrict__ lnb,
    u16* __restrict__ dwc, u16* __restrict__ norm1, const int* __restrict__ flagp)
{
  const int f = *flagp;
  const int tok = blockIdx.x;
  const int b = tok / 3136, rem = tok % 3136;
  const int hh = rem / 56, ww = rem % 56;
  const int c = threadIdx.x;
  __shared__ float kv[192];
  __shared__ float red[8];
  if (c >= 64) {
    const int j = c - 64;
    float s = ld(dwb, j, f);
    #pragma unroll
    for (int dh = -1; dh <= 1; ++dh) {
      const int h2 = hh + dh;
      if (h2 < 0 || h2 >= 56) continue;
      #pragma unroll
      for (int dw = -1; dw <= 1; ++dw) {
        const int w2 = ww + dw;
        if (w2 < 0 || w2 >= 56) continue;
        const long nb = (long)b * 3136 + h2 * 56 + w2;
        s += ld(x, nb * 256 + 64 + j, f) * ld(dwk, ((dh + 1) * 3 + dw + 1) * 192 + j, f);
      }
    }
    kv[j] = s;
  }
  __syncthreads();
  float val;
  if (c < 64) {
    val = ld(x, (long)tok * 256 + c, f);
  } else {
    const int j = c - 64, g = j >> 6, i = j & 63;
    float s = kv[i];
    if (g >= 1) s += kv[64 + i];
    if (g >= 2) s += kv[128 + i];
    val = s;
  }
  float sum = val, sq = val * val;
  #pragma unroll
  for (int m = 32; m; m >>= 1) { sum += __shfl_xor(sum, m); sq += __shfl_xor(sq, m); }
  if ((c & 63) == 0) { red[c >> 6] = sum; red[4 + (c >> 6)] = sq; }
  __syncthreads();
  const float ts = red[0] + red[1] + red[2] + red[3];
  const float tq = red[4] + red[5] + red[6] + red[7];
  const float mu = ts * (1.0f / 256.0f);
  const float var = tq * (1.0f / 256.0f) - mu * mu;
  const float rstd = rsqrtf(fmaxf(var, 0.f) + 1e-6f);
  const float nv = (val - mu) * rstd * ld(lng, c, f) + ld(lnb, c, f);
  dwc[(long)tok * 256 + c] = f2h(val);
  norm1[(long)tok * 256 + c] = f2h(nv);
}

// Generic fp16 MFMA GEMM, B transposed. EPI: 0 fp16; 2 +bias+aux(fp16)+BN fp16;
// 3 +bias gelu fp16; 4 +bias+residual(input dtype) -> out (flag dtype).
// zoff: element offset added to aux & C indices (MLP chunking).
#define LDST 40

template<int BM, int WR, int WC, int EPI>
__global__ __launch_bounds__(256) void gemm_kernel(
    const u16* __restrict__ A, const u16* __restrict__ Bt, void* C,
    int K, int lda, int ldb, int ldc,
    long aZ, long bZ, long cZ, long zoff,
    const void* __restrict__ bias, const void* aux,
    const void* __restrict__ bng, const void* __restrict__ bnb,
    const void* __restrict__ bnm, const void* __restrict__ bnv,
    const int* __restrict__ flagp)
{
  static_assert(BM == 64 || BM == 128, "");
  constexpr int BN = 128;
  constexpr int WM = BM / WR, WN = BN / WC;
  constexpr int MI = WM / 16, NI = WN / 16;
  __shared__ __align__(16) u16 As[BM * LDST];
  __shared__ __align__(16) u16 Bs[BN * LDST];
  const int f = (EPI == 0) ? 0 : *flagp;
  const int tid = threadIdx.x;
  const int wave = tid >> 6, lane = tid & 63;
  const int wr = wave / WC, wc = wave % WC;
  const int quad = lane >> 4, l16 = lane & 15;
  const int tileM = blockIdx.y * BM, tileN = blockIdx.x * BN;
  const u16* Ab = A + (long)blockIdx.z * aZ + (long)tileM * lda;
  const u16* Bb = Bt + (long)blockIdx.z * bZ + (long)tileN * ldb;
  f32x4 acc[MI][NI];
  #pragma unroll
  for (int mi = 0; mi < MI; ++mi)
    #pragma unroll
    for (int ni = 0; ni < NI; ++ni)
      acc[mi][ni] = (f32x4){0.f, 0.f, 0.f, 0.f};

  for (int k0 = 0; k0 < K; k0 += 32) {
    #pragma unroll
    for (int p = 0; p < BM / 64; ++p) {
      const int ff = p * 256 + tid;
      const int r = ff >> 2, cc = (ff & 3) * 8;
      *(f16x8*)&As[r * LDST + cc] = *(const f16x8*)(Ab + (long)r * lda + k0 + cc);
    }
    #pragma unroll
    for (int p = 0; p < 2; ++p) {
      const int ff = p * 256 + tid;
      const int r = ff >> 2, cc = (ff & 3) * 8;
      *(f16x8*)&Bs[r * LDST + cc] = *(const f16x8*)(Bb + (long)r * ldb + k0 + cc);
    }
    __syncthreads();
    f16x8 af[MI], bfr[NI];
    #pragma unroll
    for (int mi = 0; mi < MI; ++mi)
      af[mi] = *(const f16x8*)&As[(wr * WM + mi * 16 + l16) * LDST + quad * 8];
    #pragma unroll
    for (int ni = 0; ni < NI; ++ni)
      bfr[ni] = *(const f16x8*)&Bs[(wc * WN + ni * 16 + l16) * LDST + quad * 8];
    #pragma unroll
    for (int mi = 0; mi < MI; ++mi)
      #pragma unroll
      for (int ni = 0; ni < NI; ++ni)
        acc[mi][ni] = __builtin_amdgcn_mfma_f32_16x16x32_f16(af[mi], bfr[ni], acc[mi][ni], 0, 0, 0);
    __syncthreads();
  }

  const long zC = (long)blockIdx.z * cZ + zoff;
  #pragma unroll
  for (int mi = 0; mi < MI; ++mi) {
    #pragma unroll
    for (int ni = 0; ni < NI; ++ni) {
      const int col = tileN + wc * WN + ni * 16 + l16;
      #pragma unroll
      for (int r = 0; r < 4; ++r) {
        const int row = tileM + wr * WM + mi * 16 + quad * 4 + r;
        const long ci = zC + (long)row * ldc + col;
        float v = acc[mi][ni][r];
        if (EPI == 0) {
          ((u16*)C)[ci] = f2h(v);
        } else if (EPI == 2) {
          v += ld(bias, col, f);
          v += h2f(((const u16*)aux)[ci]);
          v = (v - ld(bnm, col, f)) * rsqrtf(ld(bnv, col, f) + 1e-3f) * ld(bng, col, f) + ld(bnb, col, f);
          ((u16*)C)[ci] = f2h(v);
        } else if (EPI == 3) {
          v += ld(bias, col, f);
          v = 0.5f * v * (1.0f + erff(v * 0.7071067811865475f));
          ((u16*)C)[ci] = f2h(v);
        } else {
          v += ld(bias, col, f);
          v += ld(aux, ci, f);
          if (f) ((float*)C)[ci] = v; else ((u16*)C)[ci] = f2b(v);
        }
      }
    }
  }
}

// K3: A[b,h,d,e] accumulation with l2norm folded into per-token scalar.
__global__ __launch_bounds__(256) void attn_accum_kernel(
    const u16* __restrict__ qk, float* __restrict__ A_part, int pair0)
{
  const int pl = blockIdx.x;
  const int split = blockIdx.y;
  const int bl = pl >> 3, h = pl & 7;
  const int tid = threadIdx.x;
  __shared__ float lq[16][32];
  __shared__ float lk[16][32];
  __shared__ float ls[16];
  const int d = tid >> 3;
  const int e0 = (tid & 7) * 4;
  float a0 = 0.f, a1 = 0.f, a2 = 0.f, a3 = 0.f;
  const long base = (long)bl * 3136 * 512 + h * 32;
  const int n0 = split * 448;
  for (int ch = 0; ch < 28; ++ch) {
    const int nb = n0 + ch * 16;
    #pragma unroll
    for (int rr = 0; rr < 4; ++rr) {
      const int ff = rr * 256 + tid;
      const int n = ff >> 6, half = (ff >> 5) & 1, idx = ff & 31;
      const float v = h2f(qk[base + (long)(nb + n) * 512 + half * 256 + idx]);
      if (half == 0) lq[n][idx] = v; else lk[n][idx] = v;
    }
    __syncthreads();
    {
      const int n = tid >> 4, p = tid & 15;
      float sq = lq[n][2 * p] * lq[n][2 * p] + lq[n][2 * p + 1] * lq[n][2 * p + 1];
      float sk = lk[n][2 * p] * lk[n][2 * p] + lk[n][2 * p + 1] * lk[n][2 * p + 1];
      #pragma unroll
      for (int m = 8; m; m >>= 1) { sq += __shfl_xor(sq, m); sk += __shfl_xor(sk, m); }
      if (p == 0)
        ls[n] = 0.17677669529663687f /
                (sqrtf(fmaxf(sq, 1e-12f)) * sqrtf(fmaxf(sk, 1e-12f)));
    }
    __syncthreads();
    #pragma unroll
    for (int n = 0; n < 16; ++n) {
      const float qd = lq[n][d] * ls[n];
      a0 += qd * lk[n][e0];
      a1 += qd * lk[n][e0 + 1];
      a2 += qd * lk[n][e0 + 2];
      a3 += qd * lk[n][e0 + 3];
    }
    __syncthreads();
  }
  float* o = A_part + ((long)(pair0 + pl) * SPLITN + split) * 1024 + d * 32 + e0;
  o[0] = a0; o[1] = a1; o[2] = a2; o[3] = a3;
}

__global__ __launch_bounds__(1024) void softmax_kernel(float* A_part) {
  const int pair = blockIdx.x;
  const int t = threadIdx.x;
  float v = 0.f;
  float* base = A_part + (long)pair * SPLITN * 1024 + t;
  #pragma unroll
  for (int s = 0; s < SPLITN; ++s) v += base[s * 1024];
  float mx = v;
  #pragma unroll
  for (int m = 16; m; m >>= 1) mx = fmaxf(mx, __shfl_xor(mx, m, 32));
  const float p = expf(v - mx);
  float sm = p;
  #pragma unroll
  for (int m = 16; m; m >>= 1) sm += __shfl_xor(sm, m, 32);
  base[0] = p / sm;
}

__global__ __launch_bounds__(256) void wb_kernel(
    const float* __restrict__ A_part, const void* __restrict__ proj_w,
    u16* __restrict__ Wbt, const int* __restrict__ flagp)
{
  const int f = *flagp;
  const int b = blockIdx.x;
  const int cs = blockIdx.y;
  const int tid = threadIdx.x;
  const int cg = tid & 31, dg = tid >> 5;
  const int c = cs * 32 + cg;
  __shared__ float Ah[32][32];
  __shared__ float pw[32][33];
  for (int h = 0; h < 8; ++h) {
    const float* Abase = A_part + ((long)(b * 8 + h) * SPLITN) * 1024;
    #pragma unroll
    for (int rr = 0; rr < 4; ++rr) {
      const int ff = rr * 256 + tid;
      Ah[ff >> 5][ff & 31] = Abase[ff];
    }
    #pragma unroll
    for (int rr = 0; rr < 4; ++rr) {
      const int ff = rr * 256 + tid;
      const int e = ff >> 5, ccc = ff & 31;
      pw[e][ccc] = ld(proj_w, (long)(h * 32 + e) * 256 + cs * 32 + ccc, f);
    }
    __syncthreads();
    float acc[4] = {0.f, 0.f, 0.f, 0.f};
    #pragma unroll
    for (int e = 0; e < 32; ++e) {
      const float pv = pw[e][cg];
      #pragma unroll
      for (int dd = 0; dd < 4; ++dd)
        acc[dd] += Ah[dg * 4 + dd][e] * pv;
    }
    #pragma unroll
    for (int dd = 0; dd < 4; ++dd)
      Wbt[((long)b * 256 + c) * 256 + h * 32 + dg * 4 + dd] = f2h(acc[dd]);
    __syncthreads();
  }
}

extern "C" void kernel_launch(void* const* d_in, const int* in_sizes, int n_in,
                              void* d_out, int out_size, void* d_ws, size_t ws_size,
                              hipStream_t stream) {
  const void* x      = d_in[0];
  const void* dwk    = d_in[1];
  const void* dwb    = d_in[2];
  const void* lng    = d_in[3];
  const void* lnb    = d_in[4];
  const void* qkv_w  = d_in[5];
  const void* proj_w = d_in[6];
  const void* proj_b = d_in[7];
  const void* bn_g   = d_in[8];
  const void* bn_b   = d_in[9];
  const void* bn_m   = d_in[10];
  const void* bn_v   = d_in[11];
  const void* fc1_w  = d_in[12];
  const void* fc1_b  = d_in[13];
  const void* fc2_w  = d_in[14];
  const void* fc2_b  = d_in[15];
  char* ws = (char*)d_ws;

  int*   flagp   = (int*)  (ws + 0);
  u16*   wqkvT   = (u16*)  (ws + 256);
  u16*   wfc1T   = (u16*)  (ws + 393472);
  u16*   wfc2T   = (u16*)  (ws + 917760);
  float* A_part  = (float*)(ws + 1442048);
  u16*   Wbt     = (u16*)  (ws + 5112064);
  u16*   vbuf    = (u16*)  (ws + 7209216);
  u16*   dwc     = (u16*)  (ws + 32899328);
  u16*   qk_half = (u16*)  (ws + 58589440);
  u16*   h1c     = (u16*)  (ws + 58589440);
  u16*   norm1   = (u16*)d_out;  // fp16-bit scratch; dead before fc2 writes out

  detect_kernel<<<1, 64, 0, stream>>>((const u16*)x, flagp);

  transpose_cvt_kernel<<<768, 256, 0, stream>>>(qkv_w, wqkvT, 256, 768, flagp);
  transpose_cvt_kernel<<<1024, 256, 0, stream>>>(fc1_w, wfc1T, 256, 1024, flagp);
  transpose_cvt_kernel<<<1024, 256, 0, stream>>>(fc2_w, wfc2T, 1024, 256, flagp);

  dwconv_ln_kernel<<<50176, 256, 0, stream>>>(x, dwk, dwb, lng, lnb, dwc, norm1, flagp);

  for (int half = 0; half < 2; ++half) {
    const u16* nh = norm1 + (long)half * 25088 * 256;
    gemm_kernel<128, 2, 2, 0><<<dim3(4, 196, 1), 256, 0, stream>>>(
        nh, wqkvT, qk_half, 256, 256, 256, 512, 0, 0, 0, 0,
        nullptr, nullptr, nullptr, nullptr, nullptr, nullptr, flagp);
    gemm_kernel<128, 2, 2, 0><<<dim3(2, 196, 1), 256, 0, stream>>>(
        nh, wqkvT + 512 * 256, vbuf + (long)half * 25088 * 256, 256, 256, 256, 256,
        0, 0, 0, 0, nullptr, nullptr, nullptr, nullptr, nullptr, nullptr, flagp);
    attn_accum_kernel<<<dim3(64, SPLITN), 256, 0, stream>>>(qk_half, A_part, half * 64);
  }

  softmax_kernel<<<128, 1024, 0, stream>>>(A_part);
  wb_kernel<<<dim3(16, 8), 256, 0, stream>>>(A_part, proj_w, Wbt, flagp);

  gemm_kernel<64, 1, 4, 2><<<dim3(2, 49, 16), 256, 0, stream>>>(
      vbuf, Wbt, dwc, 256, 256, 256, 256,
      (long)3136 * 256, 65536, (long)3136 * 256, 0,
      proj_b, dwc, bn_g, bn_b, bn_m, bn_v, flagp);

  for (int c2 = 0; c2 < 4; ++c2) {
    const long ro = (long)c2 * 12544 * 256;
    gemm_kernel<128, 2, 2, 3><<<dim3(8, 98, 1), 256, 0, stream>>>(
        dwc + ro, wfc1T, h1c, 256, 256, 256, 1024, 0, 0, 0, 0,
        fc1_b, nullptr, nullptr, nullptr, nullptr, nullptr, flagp);
    gemm_kernel<128, 2, 2, 4><<<dim3(2, 98, 1), 256, 0, stream>>>(
        h1c, wfc2T, d_out, 1024, 1024, 1024, 256, 0, 0, 0, ro,
        fc2_b, x, nullptr, nullptr, nullptr, nullptr, flagp);
  }
}

// Round 4
// 725.294 us; speedup vs baseline: 1.1636x; 1.1636x over previous
//
#include <hip/hip_runtime.h>
#include <cstdint>

typedef unsigned short u16;
typedef __attribute__((ext_vector_type(8))) _Float16 f16x8;
typedef __attribute__((ext_vector_type(4))) float f32x4;

#define SPLITN 7

__device__ __forceinline__ float b2f(u16 u) {
  union { unsigned int i; float f; } v; v.i = ((unsigned int)u) << 16; return v.f;
}
__device__ __forceinline__ u16 f2b(float f) {
  union { float f; unsigned int i; } v; v.f = f;
  unsigned int x = v.i;
  return (u16)((x + 0x7fffu + ((x >> 16) & 1u)) >> 16);
}
__device__ __forceinline__ u16 f2h(float f) {
  union { _Float16 h; u16 u; } v; v.h = (_Float16)f; return v.u;
}
__device__ __forceinline__ float h2f(u16 u) {
  union { u16 u; _Float16 h; } v; v.u = u; return (float)v.h;
}
// Flag-dispatched input load: f=1 -> float32 buffer, f=0 -> bf16 buffer.
__device__ __forceinline__ float ld(const void* p, long i, int f) {
  return f ? ((const float*)p)[i] : b2f(((const u16*)p)[i]);
}
template<int F>
__device__ __forceinline__ float4 ld4(const void* p, long i) {
  if (F) return *(const float4*)((const float*)p + i);
  const ushort4 u = *(const ushort4*)((const u16*)p + i);
  return make_float4(b2f(u.x), b2f(u.y), b2f(u.z), b2f(u.w));
}

// Kd: dtype sniffer. flag=1 means inputs/output are float32.
__global__ void detect_kernel(const u16* __restrict__ x, int* __restrict__ flag) {
  if (threadIdx.x == 0) {
    int bad = 0;
    for (int i = 0; i < 512; ++i) {
      const float v = fabsf(b2f(x[2 * i]));
      if (!(v < 100.f) || v < 1e-6f) ++bad;
    }
    *flag = (bad > 16) ? 1 : 0;
  }
}

// K0: weight [R][C] -> fp16 [C][R]
__global__ void transpose_cvt_kernel(const void* __restrict__ in, u16* __restrict__ out,
                                     int R, int C, const int* __restrict__ flagp) {
  const int f = *flagp;
  const int o = blockIdx.x * 256 + threadIdx.x;
  if (o < R * C) {
    const int i = o / R, j = o % R;
    out[o] = f2h(ld(in, (long)j * C + i, f));
  }
}

// ---------------------------------------------------------------------------
// K1 v2: wave-per-token dwconv + group cumsum + LN. 4 channels/lane, vector
// loads, shfl cumsum + shfl LN reduce — zero LDS, zero barriers.
template<int F>
__device__ __forceinline__ void dwconv_body(
    const void* __restrict__ x, const void* __restrict__ dwk, const void* __restrict__ dwb,
    const void* __restrict__ lng, const void* __restrict__ lnb,
    u16* __restrict__ dwc, u16* __restrict__ norm1, int tok, int lane)
{
  const int b = tok / 3136, rem = tok % 3136;
  const int hh = rem / 56, ww = rem % 56;
  const long row0 = (long)tok * 256;
  const int c0 = lane * 4;
  const float4 xv = ld4<F>(x, row0 + c0);
  float sx = 0.f, sy = 0.f, sz = 0.f, sw = 0.f;
  if (lane >= 16) {
    const int j0 = c0 - 64;
    const float4 bb = ld4<F>(dwb, j0);
    sx = bb.x; sy = bb.y; sz = bb.z; sw = bb.w;
    #pragma unroll
    for (int dh = -1; dh <= 1; ++dh) {
      const int h2 = hh + dh;
      if (h2 < 0 || h2 >= 56) continue;
      #pragma unroll
      for (int dw2 = -1; dw2 <= 1; ++dw2) {
        const int w2 = ww + dw2;
        if (w2 < 0 || w2 >= 56) continue;
        const long nb = ((long)b * 3136 + h2 * 56 + w2) * 256;
        const float4 xt = ld4<F>(x, nb + c0);
        const float4 wt = ld4<F>(dwk, (long)((dh + 1) * 3 + (dw2 + 1)) * 192 + j0);
        sx += xt.x * wt.x; sy += xt.y * wt.y; sz += xt.z * wt.z; sw += xt.w * wt.w;
      }
    }
  }
  // cumsum over groups: lanes 16-31 g1 (own), 32-47 g2 (+lane-16), 48-63 g3 (+lane-32)
  const float t1x = __shfl(sx, lane - 16), t1y = __shfl(sy, lane - 16),
              t1z = __shfl(sz, lane - 16), t1w = __shfl(sw, lane - 16);
  const float t2x = __shfl(sx, lane - 32), t2y = __shfl(sy, lane - 32),
              t2z = __shfl(sz, lane - 32), t2w = __shfl(sw, lane - 32);
  if (lane >= 32) { sx += t1x; sy += t1y; sz += t1z; sw += t1w; }
  if (lane >= 48) { sx += t2x; sy += t2y; sz += t2z; sw += t2w; }
  float vx, vy, vz, vw;
  if (lane < 16) { vx = xv.x; vy = xv.y; vz = xv.z; vw = xv.w; }
  else           { vx = sx;   vy = sy;   vz = sz;   vw = sw;   }
  float sum = vx + vy + vz + vw;
  float sq = vx * vx + vy * vy + vz * vz + vw * vw;
  #pragma unroll
  for (int m = 32; m; m >>= 1) { sum += __shfl_xor(sum, m); sq += __shfl_xor(sq, m); }
  const float mu = sum * (1.0f / 256.0f);
  const float var = sq * (1.0f / 256.0f) - mu * mu;
  const float rstd = rsqrtf(fmaxf(var, 0.f) + 1e-6f);
  const float4 g = ld4<F>(lng, c0);
  const float4 be = ld4<F>(lnb, c0);
  ushort4 dv, nv;
  dv.x = f2h(vx); dv.y = f2h(vy); dv.z = f2h(vz); dv.w = f2h(vw);
  nv.x = f2h((vx - mu) * rstd * g.x + be.x);
  nv.y = f2h((vy - mu) * rstd * g.y + be.y);
  nv.z = f2h((vz - mu) * rstd * g.z + be.z);
  nv.w = f2h((vw - mu) * rstd * g.w + be.w);
  *(ushort4*)(dwc + row0 + c0) = dv;
  *(ushort4*)(norm1 + row0 + c0) = nv;
}

__global__ __launch_bounds__(256) void dwconv_ln_kernel(
    const void* __restrict__ x, const void* __restrict__ dwk, const void* __restrict__ dwb,
    const void* __restrict__ lng, const void* __restrict__ lnb,
    u16* __restrict__ dwc, u16* __restrict__ norm1, const int* __restrict__ flagp)
{
  const int wave = threadIdx.x >> 6, lane = threadIdx.x & 63;
  const int tok = blockIdx.x * 4 + wave;
  if (*flagp) dwconv_body<1>(x, dwk, dwb, lng, lnb, dwc, norm1, tok, lane);
  else        dwconv_body<0>(x, dwk, dwb, lng, lnb, dwc, norm1, tok, lane);
}

// ---------------------------------------------------------------------------
// Generic fp16 MFMA GEMM, m97-style global_load_lds staging (16B/lane,
// wave-uniform LDS base, unpadded 32-half rows). B supplied transposed.
// EPI: 0 fp16; 2 +bias+aux(fp16)+BN fp16; 3 +bias gelu fp16;
//      4 +bias+residual(input dtype) -> out (flag dtype). zoff: elem offset on C/aux.
template<int BM, int WR, int WC, int EPI>
__global__ __launch_bounds__(256) void gemm_kernel(
    const u16* __restrict__ A, const u16* __restrict__ Bt, void* C,
    int K, int lda, int ldb, int ldc,
    long aZ, long bZ, long cZ, long zoff,
    const void* __restrict__ bias, const void* aux,
    const void* __restrict__ bng, const void* __restrict__ bnb,
    const void* __restrict__ bnm, const void* __restrict__ bnv,
    const int* __restrict__ flagp)
{
  static_assert(BM == 64 || BM == 128, "");
  constexpr int BN = 128;
  constexpr int WM = BM / WR, WN = BN / WC;
  constexpr int MI = WM / 16, NI = WN / 16;
  __shared__ __align__(16) u16 As[BM * 32];
  __shared__ __align__(16) u16 Bs[BN * 32];
  const int f = (EPI == 0) ? 0 : *flagp;
  const int tid = threadIdx.x;
  const int wave = tid >> 6, lane = tid & 63;
  const int wr = wave / WC, wc = wave % WC;
  const int quad = lane >> 4, l16 = lane & 15;
  const int tileM = blockIdx.y * BM, tileN = blockIdx.x * BN;
  const u16* Ab = A + (long)blockIdx.z * aZ + (long)tileM * lda;
  const u16* Bb = Bt + (long)blockIdx.z * bZ + (long)tileN * ldb;
  const int sr = lane >> 2;       // row within a 16-row chunk
  const int sc = (lane & 3) * 8;  // half-offset within row (16B granules)
  f32x4 acc[MI][NI];
  #pragma unroll
  for (int mi = 0; mi < MI; ++mi)
    #pragma unroll
    for (int ni = 0; ni < NI; ++ni)
      acc[mi][ni] = (f32x4){0.f, 0.f, 0.f, 0.f};

  for (int k0 = 0; k0 < K; k0 += 32) {
    #pragma unroll
    for (int j = 0; j < BM / 64; ++j) {
      const int chunk = wave * (BM / 64) + j;
      const u16* g = Ab + (long)(chunk * 16 + sr) * lda + k0 + sc;
      __builtin_amdgcn_global_load_lds(
          (const __attribute__((address_space(1))) void*)g,
          (__attribute__((address_space(3))) void*)(As + chunk * 512), 16, 0, 0);
    }
    #pragma unroll
    for (int j = 0; j < 2; ++j) {
      const int chunk = wave * 2 + j;
      const u16* g = Bb + (long)(chunk * 16 + sr) * ldb + k0 + sc;
      __builtin_amdgcn_global_load_lds(
          (const __attribute__((address_space(1))) void*)g,
          (__attribute__((address_space(3))) void*)(Bs + chunk * 512), 16, 0, 0);
    }
    __syncthreads();
    f16x8 af[MI], bfr[NI];
    #pragma unroll
    for (int mi = 0; mi < MI; ++mi)
      af[mi] = *(const f16x8*)&As[(wr * WM + mi * 16 + l16) * 32 + quad * 8];
    #pragma unroll
    for (int ni = 0; ni < NI; ++ni)
      bfr[ni] = *(const f16x8*)&Bs[(wc * WN + ni * 16 + l16) * 32 + quad * 8];
    #pragma unroll
    for (int mi = 0; mi < MI; ++mi)
      #pragma unroll
      for (int ni = 0; ni < NI; ++ni)
        acc[mi][ni] = __builtin_amdgcn_mfma_f32_16x16x32_f16(af[mi], bfr[ni], acc[mi][ni], 0, 0, 0);
    __syncthreads();
  }

  const long zC = (long)blockIdx.z * cZ + zoff;
  #pragma unroll
  for (int mi = 0; mi < MI; ++mi) {
    #pragma unroll
    for (int ni = 0; ni < NI; ++ni) {
      const int col = tileN + wc * WN + ni * 16 + l16;
      #pragma unroll
      for (int r = 0; r < 4; ++r) {
        const int row = tileM + wr * WM + mi * 16 + quad * 4 + r;
        const long ci = zC + (long)row * ldc + col;
        float v = acc[mi][ni][r];
        if (EPI == 0) {
          ((u16*)C)[ci] = f2h(v);
        } else if (EPI == 2) {
          v += ld(bias, col, f);
          v += h2f(((const u16*)aux)[ci]);
          v = (v - ld(bnm, col, f)) * rsqrtf(ld(bnv, col, f) + 1e-3f) * ld(bng, col, f) + ld(bnb, col, f);
          ((u16*)C)[ci] = f2h(v);
        } else if (EPI == 3) {
          v += ld(bias, col, f);
          v = 0.5f * v * (1.0f + erff(v * 0.7071067811865475f));
          ((u16*)C)[ci] = f2h(v);
        } else {
          v += ld(bias, col, f);
          v += ld(aux, ci, f);
          if (f) ((float*)C)[ci] = v; else ((u16*)C)[ci] = f2b(v);
        }
      }
    }
  }
}

// ---------------------------------------------------------------------------
// K3: A[b,h,d,e] accumulation with l2norm folded into per-token scalar.
__global__ __launch_bounds__(256) void attn_accum_kernel(
    const u16* __restrict__ qk, float* __restrict__ A_part, int pair0)
{
  const int pl = blockIdx.x;
  const int split = blockIdx.y;
  const int bl = pl >> 3, h = pl & 7;
  const int tid = threadIdx.x;
  __shared__ float lq[16][32];
  __shared__ float lk[16][32];
  __shared__ float ls[16];
  const int d = tid >> 3;
  const int e0 = (tid & 7) * 4;
  float a0 = 0.f, a1 = 0.f, a2 = 0.f, a3 = 0.f;
  const long base = (long)bl * 3136 * 512 + h * 32;
  const int n0 = split * 448;
  for (int ch = 0; ch < 28; ++ch) {
    const int nb = n0 + ch * 16;
    #pragma unroll
    for (int rr = 0; rr < 4; ++rr) {
      const int ff = rr * 256 + tid;
      const int n = ff >> 6, half = (ff >> 5) & 1, idx = ff & 31;
      const float v = h2f(qk[base + (long)(nb + n) * 512 + half * 256 + idx]);
      if (half == 0) lq[n][idx] = v; else lk[n][idx] = v;
    }
    __syncthreads();
    {
      const int n = tid >> 4, p = tid & 15;
      float sq = lq[n][2 * p] * lq[n][2 * p] + lq[n][2 * p + 1] * lq[n][2 * p + 1];
      float sk = lk[n][2 * p] * lk[n][2 * p] + lk[n][2 * p + 1] * lk[n][2 * p + 1];
      #pragma unroll
      for (int m = 8; m; m >>= 1) { sq += __shfl_xor(sq, m); sk += __shfl_xor(sk, m); }
      if (p == 0)
        ls[n] = 0.17677669529663687f /
                (sqrtf(fmaxf(sq, 1e-12f)) * sqrtf(fmaxf(sk, 1e-12f)));
    }
    __syncthreads();
    #pragma unroll
    for (int n = 0; n < 16; ++n) {
      const float qd = lq[n][d] * ls[n];
      a0 += qd * lk[n][e0];
      a1 += qd * lk[n][e0 + 1];
      a2 += qd * lk[n][e0 + 2];
      a3 += qd * lk[n][e0 + 3];
    }
    __syncthreads();
  }
  float* o = A_part + ((long)(pair0 + pl) * SPLITN + split) * 1024 + d * 32 + e0;
  o[0] = a0; o[1] = a1; o[2] = a2; o[3] = a3;
}

__global__ __launch_bounds__(1024) void softmax_kernel(float* A_part) {
  const int pair = blockIdx.x;
  const int t = threadIdx.x;
  float v = 0.f;
  float* base = A_part + (long)pair * SPLITN * 1024 + t;
  #pragma unroll
  for (int s = 0; s < SPLITN; ++s) v += base[s * 1024];
  float mx = v;
  #pragma unroll
  for (int m = 16; m; m >>= 1) mx = fmaxf(mx, __shfl_xor(mx, m, 32));
  const float p = expf(v - mx);
  float sm = p;
  #pragma unroll
  for (int m = 16; m; m >>= 1) sm += __shfl_xor(sm, m, 32);
  base[0] = p / sm;
}

__global__ __launch_bounds__(256) void wb_kernel(
    const float* __restrict__ A_part, const void* __restrict__ proj_w,
    u16* __restrict__ Wbt, const int* __restrict__ flagp)
{
  const int f = *flagp;
  const int b = blockIdx.x;
  const int cs = blockIdx.y;
  const int tid = threadIdx.x;
  const int cg = tid & 31, dg = tid >> 5;
  const int c = cs * 32 + cg;
  __shared__ float Ah[32][32];
  __shared__ float pw[32][33];
  for (int h = 0; h < 8; ++h) {
    const float* Abase = A_part + ((long)(b * 8 + h) * SPLITN) * 1024;
    #pragma unroll
    for (int rr = 0; rr < 4; ++rr) {
      const int ff = rr * 256 + tid;
      Ah[ff >> 5][ff & 31] = Abase[ff];
    }
    #pragma unroll
    for (int rr = 0; rr < 4; ++rr) {
      const int ff = rr * 256 + tid;
      const int e = ff >> 5, ccc = ff & 31;
      pw[e][ccc] = ld(proj_w, (long)(h * 32 + e) * 256 + cs * 32 + ccc, f);
    }
    __syncthreads();
    float acc[4] = {0.f, 0.f, 0.f, 0.f};
    #pragma unroll
    for (int e = 0; e < 32; ++e) {
      const float pv = pw[e][cg];
      #pragma unroll
      for (int dd = 0; dd < 4; ++dd)
        acc[dd] += Ah[dg * 4 + dd][e] * pv;
    }
    #pragma unroll
    for (int dd = 0; dd < 4; ++dd)
      Wbt[((long)b * 256 + c) * 256 + h * 32 + dg * 4 + dd] = f2h(acc[dd]);
    __syncthreads();
  }
}

extern "C" void kernel_launch(void* const* d_in, const int* in_sizes, int n_in,
                              void* d_out, int out_size, void* d_ws, size_t ws_size,
                              hipStream_t stream) {
  const void* x      = d_in[0];
  const void* dwk    = d_in[1];
  const void* dwb    = d_in[2];
  const void* lng    = d_in[3];
  const void* lnb    = d_in[4];
  const void* qkv_w  = d_in[5];
  const void* proj_w = d_in[6];
  const void* proj_b = d_in[7];
  const void* bn_g   = d_in[8];
  const void* bn_b   = d_in[9];
  const void* bn_m   = d_in[10];
  const void* bn_v   = d_in[11];
  const void* fc1_w  = d_in[12];
  const void* fc1_b  = d_in[13];
  const void* fc2_w  = d_in[14];
  const void* fc2_b  = d_in[15];
  char* ws = (char*)d_ws;

  int*   flagp   = (int*)  (ws + 0);
  u16*   wqkvT   = (u16*)  (ws + 256);
  u16*   wfc1T   = (u16*)  (ws + 393472);
  u16*   wfc2T   = (u16*)  (ws + 917760);
  float* A_part  = (float*)(ws + 1442048);
  u16*   Wbt     = (u16*)  (ws + 5112064);
  u16*   vbuf    = (u16*)  (ws + 7209216);
  u16*   dwc     = (u16*)  (ws + 32899328);
  u16*   qk_half = (u16*)  (ws + 58589440);
  u16*   h1c     = (u16*)  (ws + 58589440);
  u16*   norm1   = (u16*)d_out;  // fp16-bit scratch; dead before fc2 writes out

  detect_kernel<<<1, 64, 0, stream>>>((const u16*)x, flagp);

  transpose_cvt_kernel<<<768, 256, 0, stream>>>(qkv_w, wqkvT, 256, 768, flagp);
  transpose_cvt_kernel<<<1024, 256, 0, stream>>>(fc1_w, wfc1T, 256, 1024, flagp);
  transpose_cvt_kernel<<<1024, 256, 0, stream>>>(fc2_w, wfc2T, 1024, 256, flagp);

  dwconv_ln_kernel<<<12544, 256, 0, stream>>>(x, dwk, dwb, lng, lnb, dwc, norm1, flagp);

  for (int half = 0; half < 2; ++half) {
    const u16* nh = norm1 + (long)half * 25088 * 256;
    gemm_kernel<128, 2, 2, 0><<<dim3(4, 196, 1), 256, 0, stream>>>(
        nh, wqkvT, qk_half, 256, 256, 256, 512, 0, 0, 0, 0,
        nullptr, nullptr, nullptr, nullptr, nullptr, nullptr, flagp);
    gemm_kernel<128, 2, 2, 0><<<dim3(2, 196, 1), 256, 0, stream>>>(
        nh, wqkvT + 512 * 256, vbuf + (long)half * 25088 * 256, 256, 256, 256, 256,
        0, 0, 0, 0, nullptr, nullptr, nullptr, nullptr, nullptr, nullptr, flagp);
    attn_accum_kernel<<<dim3(64, SPLITN), 256, 0, stream>>>(qk_half, A_part, half * 64);
  }

  softmax_kernel<<<128, 1024, 0, stream>>>(A_part);
  wb_kernel<<<dim3(16, 8), 256, 0, stream>>>(A_part, proj_w, Wbt, flagp);

  gemm_kernel<64, 1, 4, 2><<<dim3(2, 49, 16), 256, 0, stream>>>(
      vbuf, Wbt, dwc, 256, 256, 256, 256,
      (long)3136 * 256, 65536, (long)3136 * 256, 0,
      proj_b, dwc, bn_g, bn_b, bn_m, bn_v, flagp);

  for (int c2 = 0; c2 < 4; ++c2) {
    const long ro = (long)c2 * 12544 * 256;
    gemm_kernel<128, 2, 2, 3><<<dim3(8, 98, 1), 256, 0, stream>>>(
        dwc + ro, wfc1T, h1c, 256, 256, 256, 1024, 0, 0, 0, 0,
        fc1_b, nullptr, nullptr, nullptr, nullptr, nullptr, flagp);
    gemm_kernel<64, 1, 4, 4><<<dim3(2, 196, 1), 256, 0, stream>>>(
        h1c, wfc2T, d_out, 1024, 1024, 1024, 256, 0, 0, 0, ro,
        fc2_b, x, nullptr, nullptr, nullptr, nullptr, flagp);
  }
}

// Round 5
// 565.777 us; speedup vs baseline: 1.4917x; 1.2819x over previous
//
#include <hip/hip_runtime.h>
#include <cstdint>

typedef unsigned short u16;
typedef __attribute__((ext_vector_type(8))) _Float16 f16x8;
typedef __attribute__((ext_vector_type(8))) unsigned short u16x8;
typedef __attribute__((ext_vector_type(4))) float f32x4;

#define SPLITN 7

__device__ __forceinline__ float b2f(u16 u) {
  union { unsigned int i; float f; } v; v.i = ((unsigned int)u) << 16; return v.f;
}
__device__ __forceinline__ u16 f2b(float f) {
  union { float f; unsigned int i; } v; v.f = f;
  unsigned int x = v.i;
  return (u16)((x + 0x7fffu + ((x >> 16) & 1u)) >> 16);
}
__device__ __forceinline__ u16 f2h(float f) {
  union { _Float16 h; u16 u; } v; v.h = (_Float16)f; return v.u;
}
__device__ __forceinline__ float h2f(u16 u) {
  union { u16 u; _Float16 h; } v; v.u = u; return (float)v.h;
}
__device__ __forceinline__ float ld(const void* p, long i, int f) {
  return f ? ((const float*)p)[i] : b2f(((const u16*)p)[i]);
}
template<int F>
__device__ __forceinline__ float4 ld4(const void* p, long i) {
  if (F) return *(const float4*)((const float*)p + i);
  const ushort4 u = *(const ushort4*)((const u16*)p + i);
  return make_float4(b2f(u.x), b2f(u.y), b2f(u.z), b2f(u.w));
}

// Kd: dtype sniffer (parallel). flag=1 -> inputs/output are float32.
__global__ __launch_bounds__(256) void detect_kernel(const u16* __restrict__ x,
                                                     int* __restrict__ flag) {
  __shared__ int sbad;
  if (threadIdx.x == 0) sbad = 0;
  __syncthreads();
  int b = 0;
  #pragma unroll
  for (int rr = 0; rr < 2; ++rr) {
    const int i = rr * 256 + threadIdx.x;
    const float v = fabsf(b2f(x[2 * i]));
    if (!(v < 100.f) || v < 1e-6f) ++b;
  }
  atomicAdd(&sbad, b);
  __syncthreads();
  if (threadIdx.x == 0) *flag = (sbad > 16) ? 1 : 0;
}

// K0: all three weight transposes in one dispatch. [R][C] -> fp16 [C][R].
__global__ void transpose_cvt_kernel(const void* __restrict__ w0, u16* __restrict__ o0,
                                     const void* __restrict__ w1, u16* __restrict__ o1,
                                     const void* __restrict__ w2, u16* __restrict__ o2,
                                     const int* __restrict__ flagp) {
  const int f = *flagp;
  int bb = blockIdx.x;
  const void* in; u16* out; int R, C;
  if (bb < 768)       { in = w0; out = o0; R = 256;  C = 768;  }
  else if (bb < 1792) { in = w1; out = o1; R = 256;  C = 1024; bb -= 768; }
  else                { in = w2; out = o2; R = 1024; C = 256;  bb -= 1792; }
  const int o = bb * 256 + threadIdx.x;
  if (o < R * C) {
    const int i = o / R, j = o % R;
    out[o] = f2h(ld(in, (long)j * C + i, f));
  }
}

// ---------------------------------------------------------------------------
// K1: wave-per-token dwconv + group cumsum + LN. 4 channels/lane, zero LDS.
template<int F>
__device__ __forceinline__ void dwconv_body(
    const void* __restrict__ x, const void* __restrict__ dwk, const void* __restrict__ dwb,
    const void* __restrict__ lng, const void* __restrict__ lnb,
    u16* __restrict__ dwc, u16* __restrict__ norm1, int tok, int lane)
{
  const int b = tok / 3136, rem = tok % 3136;
  const int hh = rem / 56, ww = rem % 56;
  const long row0 = (long)tok * 256;
  const int c0 = lane * 4;
  const float4 xv = ld4<F>(x, row0 + c0);
  float sx = 0.f, sy = 0.f, sz = 0.f, sw = 0.f;
  if (lane >= 16) {
    const int j0 = c0 - 64;
    const float4 bb = ld4<F>(dwb, j0);
    sx = bb.x; sy = bb.y; sz = bb.z; sw = bb.w;
    #pragma unroll
    for (int dh = -1; dh <= 1; ++dh) {
      const int h2 = hh + dh;
      if (h2 < 0 || h2 >= 56) continue;
      #pragma unroll
      for (int dw2 = -1; dw2 <= 1; ++dw2) {
        const int w2 = ww + dw2;
        if (w2 < 0 || w2 >= 56) continue;
        const long nb = ((long)b * 3136 + h2 * 56 + w2) * 256;
        const float4 xt = ld4<F>(x, nb + c0);
        const float4 wt = ld4<F>(dwk, (long)((dh + 1) * 3 + (dw2 + 1)) * 192 + j0);
        sx += xt.x * wt.x; sy += xt.y * wt.y; sz += xt.z * wt.z; sw += xt.w * wt.w;
      }
    }
  }
  const float t1x = __shfl(sx, lane - 16), t1y = __shfl(sy, lane - 16),
              t1z = __shfl(sz, lane - 16), t1w = __shfl(sw, lane - 16);
  const float t2x = __shfl(sx, lane - 32), t2y = __shfl(sy, lane - 32),
              t2z = __shfl(sz, lane - 32), t2w = __shfl(sw, lane - 32);
  if (lane >= 32) { sx += t1x; sy += t1y; sz += t1z; sw += t1w; }
  if (lane >= 48) { sx += t2x; sy += t2y; sz += t2z; sw += t2w; }
  float vx, vy, vz, vw;
  if (lane < 16) { vx = xv.x; vy = xv.y; vz = xv.z; vw = xv.w; }
  else           { vx = sx;   vy = sy;   vz = sz;   vw = sw;   }
  float sum = vx + vy + vz + vw;
  float sq = vx * vx + vy * vy + vz * vz + vw * vw;
  #pragma unroll
  for (int m = 32; m; m >>= 1) { sum += __shfl_xor(sum, m); sq += __shfl_xor(sq, m); }
  const float mu = sum * (1.0f / 256.0f);
  const float var = sq * (1.0f / 256.0f) - mu * mu;
  const float rstd = rsqrtf(fmaxf(var, 0.f) + 1e-6f);
  const float4 g = ld4<F>(lng, c0);
  const float4 be = ld4<F>(lnb, c0);
  ushort4 dv, nv;
  dv.x = f2h(vx); dv.y = f2h(vy); dv.z = f2h(vz); dv.w = f2h(vw);
  nv.x = f2h((vx - mu) * rstd * g.x + be.x);
  nv.y = f2h((vy - mu) * rstd * g.y + be.y);
  nv.z = f2h((vz - mu) * rstd * g.z + be.z);
  nv.w = f2h((vw - mu) * rstd * g.w + be.w);
  *(ushort4*)(dwc + row0 + c0) = dv;
  *(ushort4*)(norm1 + row0 + c0) = nv;
}

__global__ __launch_bounds__(256) void dwconv_ln_kernel(
    const void* __restrict__ x, const void* __restrict__ dwk, const void* __restrict__ dwb,
    const void* __restrict__ lng, const void* __restrict__ lnb,
    u16* __restrict__ dwc, u16* __restrict__ norm1, const int* __restrict__ flagp)
{
  const int wave = threadIdx.x >> 6, lane = threadIdx.x & 63;
  const int tok = blockIdx.x * 4 + wave;
  if (*flagp) dwconv_body<1>(x, dwk, dwb, lng, lnb, dwc, norm1, tok, lane);
  else        dwconv_body<0>(x, dwk, dwb, lng, lnb, dwc, norm1, tok, lane);
}

// ---------------------------------------------------------------------------
// Generic fp16 MFMA GEMM, m97 global_load_lds staging, B transposed, K templated.
// EPI: 0 fp16; 2 +bias+aux(fp16)+BN fp16; 3 +bias gelu fp16;
//      4 +bias+residual(input dtype) -> flag dtype; 5 split C: cols<512 -> C
//      (qk, ldc 512), cols>=512 -> aux (v, ldc 256, +zoff).
template<int BM, int WR, int WC, int EPI, int KT>
__global__ __launch_bounds__(256) void gemm_kernel(
    const u16* __restrict__ A, const u16* __restrict__ Bt, void* C,
    int lda, int ldb, int ldc,
    long aZ, long bZ, long cZ, long zoff,
    const void* __restrict__ bias, const void* aux,
    const void* __restrict__ bng, const void* __restrict__ bnb,
    const void* __restrict__ bnm, const void* __restrict__ bnv,
    const int* __restrict__ flagp)
{
  static_assert(BM == 64 || BM == 128, "");
  constexpr int BN = 128;
  constexpr int WM = BM / WR, WN = BN / WC;
  constexpr int MI = WM / 16, NI = WN / 16;
  __shared__ __align__(16) u16 As[BM * 32];
  __shared__ __align__(16) u16 Bs[BN * 32];
  const int f = (EPI == 0 || EPI == 5) ? 0 : *flagp;
  const int tid = threadIdx.x;
  const int wave = tid >> 6, lane = tid & 63;
  const int wr = wave / WC, wc = wave % WC;
  const int quad = lane >> 4, l16 = lane & 15;
  const int tileM = blockIdx.y * BM, tileN = blockIdx.x * BN;
  const u16* Ab = A + (long)blockIdx.z * aZ + (long)tileM * lda;
  const u16* Bb = Bt + (long)blockIdx.z * bZ + (long)tileN * ldb;
  const int sr = lane >> 2;
  const int sc = (lane & 3) * 8;
  f32x4 acc[MI][NI];
  #pragma unroll
  for (int mi = 0; mi < MI; ++mi)
    #pragma unroll
    for (int ni = 0; ni < NI; ++ni)
      acc[mi][ni] = (f32x4){0.f, 0.f, 0.f, 0.f};

  for (int k0 = 0; k0 < KT; k0 += 32) {
    #pragma unroll
    for (int j = 0; j < BM / 64; ++j) {
      const int chunk = wave * (BM / 64) + j;
      const u16* g = Ab + (long)(chunk * 16 + sr) * lda + k0 + sc;
      __builtin_amdgcn_global_load_lds(
          (const __attribute__((address_space(1))) void*)g,
          (__attribute__((address_space(3))) void*)(As + chunk * 512), 16, 0, 0);
    }
    #pragma unroll
    for (int j = 0; j < 2; ++j) {
      const int chunk = wave * 2 + j;
      const u16* g = Bb + (long)(chunk * 16 + sr) * ldb + k0 + sc;
      __builtin_amdgcn_global_load_lds(
          (const __attribute__((address_space(1))) void*)g,
          (__attribute__((address_space(3))) void*)(Bs + chunk * 512), 16, 0, 0);
    }
    __syncthreads();
    f16x8 af[MI], bfr[NI];
    #pragma unroll
    for (int mi = 0; mi < MI; ++mi)
      af[mi] = *(const f16x8*)&As[(wr * WM + mi * 16 + l16) * 32 + quad * 8];
    #pragma unroll
    for (int ni = 0; ni < NI; ++ni)
      bfr[ni] = *(const f16x8*)&Bs[(wc * WN + ni * 16 + l16) * 32 + quad * 8];
    #pragma unroll
    for (int mi = 0; mi < MI; ++mi)
      #pragma unroll
      for (int ni = 0; ni < NI; ++ni)
        acc[mi][ni] = __builtin_amdgcn_mfma_f32_16x16x32_f16(af[mi], bfr[ni], acc[mi][ni], 0, 0, 0);
    __syncthreads();
  }

  const long zC = (long)blockIdx.z * cZ + ((EPI == 5) ? 0 : zoff);
  #pragma unroll
  for (int mi = 0; mi < MI; ++mi) {
    #pragma unroll
    for (int ni = 0; ni < NI; ++ni) {
      const int col = tileN + wc * WN + ni * 16 + l16;
      #pragma unroll
      for (int r = 0; r < 4; ++r) {
        const int row = tileM + wr * WM + mi * 16 + quad * 4 + r;
        const long ci = zC + (long)row * ldc + col;
        float v = acc[mi][ni][r];
        if (EPI == 0) {
          ((u16*)C)[ci] = f2h(v);
        } else if (EPI == 2) {
          v += ld(bias, col, f);
          v += h2f(((const u16*)aux)[ci]);
          v = (v - ld(bnm, col, f)) * rsqrtf(ld(bnv, col, f) + 1e-3f) * ld(bng, col, f) + ld(bnb, col, f);
          ((u16*)C)[ci] = f2h(v);
        } else if (EPI == 3) {
          v += ld(bias, col, f);
          v = 0.5f * v * (1.0f + erff(v * 0.7071067811865475f));
          ((u16*)C)[ci] = f2h(v);
        } else if (EPI == 4) {
          v += ld(bias, col, f);
          v += ld(aux, ci, f);
          if (f) ((float*)C)[ci] = v; else ((u16*)C)[ci] = f2b(v);
        } else {  // EPI == 5: qk (cols 0..511) / v (cols 512..767) split
          if (col < 512) ((u16*)C)[(long)row * 512 + col] = f2h(v);
          else ((u16*)aux)[zoff + (long)row * 256 + (col - 512)] = f2h(v);
        }
      }
    }
  }
}

// ---------------------------------------------------------------------------
// K3 v2: MFMA attention accumulation. Block = (pair, split); 7 chunks x 64 tok.
// Stage q' (l2norm scalar folded) and k transposed into LDS (XOR-8-block
// swizzle kills store bank conflicts), each wave MFMAs one 16x16 quadrant.
__global__ __launch_bounds__(256) void attn_accum_kernel(
    const u16* __restrict__ qk, float* __restrict__ A_part, int pair0)
{
  const int pl = blockIdx.x;
  const int split = blockIdx.y;
  const int bl = pl >> 3, h = pl & 7;
  const int tid = threadIdx.x;
  const int wave = tid >> 6, lane = tid & 63;
  const int quad = lane >> 4, l16 = lane & 15;
  const int dq = wave >> 1, eq = wave & 1;
  __shared__ __align__(16) u16 lqT[32 * 72];
  __shared__ __align__(16) u16 lkT[32 * 72];
  const long rowbase = (long)bl * 3136 * 512;
  const int n0 = split * 448;
  f32x4 acc = (f32x4){0.f, 0.f, 0.f, 0.f};
  const int seg = tid & 7;

  for (int ch = 0; ch < 7; ++ch) {
    const int nb = n0 + ch * 64;
    #pragma unroll
    for (int rr = 0; rr < 2; ++rr) {
      const int a = rr * 256 + tid;
      const int nl = a >> 3;  // token-in-chunk 0..63
      const int co = (seg < 4) ? h * 32 + seg * 8 : 256 + h * 32 + (seg - 4) * 8;
      const u16x8 v8 = *(const u16x8*)(qk + rowbase + (long)(nb + nl) * 512 + co);
      float vf[8], p = 0.f;
      #pragma unroll
      for (int i = 0; i < 8; ++i) { vf[i] = h2f(v8[i]); p += vf[i] * vf[i]; }
      float p1 = p + __shfl_xor(p, 1);
      float p2 = p1 + __shfl_xor(p1, 2);          // segs 0-3: ssq, segs 4-7: ssk
      const float other = __shfl_xor(p2, 4);
      const float ssq = (seg < 4) ? p2 : other;
      const float ssk = (seg < 4) ? other : p2;
      const float s = 0.17677669529663687f * rsqrtf(fmaxf(ssq, 1e-12f)) *
                      rsqrtf(fmaxf(ssk, 1e-12f));
      if (seg < 4) {
        const int db = seg * 8;
        #pragma unroll
        for (int i = 0; i < 8; ++i) {
          const int d = db + i;
          lqT[d * 72 + (nl ^ (d & 24))] = f2h(vf[i] * s);
        }
      } else {
        const int eb = (seg - 4) * 8;
        #pragma unroll
        for (int i = 0; i < 8; ++i) {
          const int e = eb + i;
          lkT[e * 72 + (nl ^ (e & 24))] = v8[i];  // raw fp16 bits, unscaled
        }
      }
    }
    __syncthreads();
    #pragma unroll
    for (int ks = 0; ks < 2; ++ks) {
      const int tb = ks * 32 + quad * 8;
      const int dA = dq * 16 + l16;
      const int eB = eq * 16 + l16;
      const f16x8 af = *(const f16x8*)&lqT[dA * 72 + (tb ^ (dA & 24))];
      const f16x8 bf = *(const f16x8*)&lkT[eB * 72 + (tb ^ (eB & 24))];
      acc = __builtin_amdgcn_mfma_f32_16x16x32_f16(af, bf, acc, 0, 0, 0);
    }
    __syncthreads();
  }
  float* o = A_part + ((long)(pair0 + pl) * SPLITN + split) * 1024;
  #pragma unroll
  for (int r = 0; r < 4; ++r)
    o[(dq * 16 + quad * 4 + r) * 32 + eq * 16 + l16] = acc[r];
}

__global__ __launch_bounds__(1024) void softmax_kernel(float* A_part) {
  const int pair = blockIdx.x;
  const int t = threadIdx.x;
  float v = 0.f;
  float* base = A_part + (long)pair * SPLITN * 1024 + t;
  #pragma unroll
  for (int s = 0; s < SPLITN; ++s) v += base[s * 1024];
  float mx = v;
  #pragma unroll
  for (int m = 16; m; m >>= 1) mx = fmaxf(mx, __shfl_xor(mx, m, 32));
  const float p = expf(v - mx);
  float sm = p;
  #pragma unroll
  for (int m = 16; m; m >>= 1) sm += __shfl_xor(sm, m, 32);
  base[0] = p / sm;
}

__global__ __launch_bounds__(256) void wb_kernel(
    const float* __restrict__ A_part, const void* __restrict__ proj_w,
    u16* __restrict__ Wbt, const int* __restrict__ flagp)
{
  const int f = *flagp;
  const int b = blockIdx.x;
  const int cs = blockIdx.y;
  const int tid = threadIdx.x;
  const int cg = tid & 31, dg = tid >> 5;
  const int c = cs * 32 + cg;
  __shared__ float Ah[32][32];
  __shared__ float pw[32][33];
  for (int h = 0; h < 8; ++h) {
    const float* Abase = A_part + ((long)(b * 8 + h) * SPLITN) * 1024;
    #pragma unroll
    for (int rr = 0; rr < 4; ++rr) {
      const int ff = rr * 256 + tid;
      Ah[ff >> 5][ff & 31] = Abase[ff];
    }
    #pragma unroll
    for (int rr = 0; rr < 4; ++rr) {
      const int ff = rr * 256 + tid;
      const int e = ff >> 5, ccc = ff & 31;
      pw[e][ccc] = ld(proj_w, (long)(h * 32 + e) * 256 + cs * 32 + ccc, f);
    }
    __syncthreads();
    float acc[4] = {0.f, 0.f, 0.f, 0.f};
    #pragma unroll
    for (int e = 0; e < 32; ++e) {
      const float pv = pw[e][cg];
      #pragma unroll
      for (int dd = 0; dd < 4; ++dd)
        acc[dd] += Ah[dg * 4 + dd][e] * pv;
    }
    #pragma unroll
    for (int dd = 0; dd < 4; ++dd)
      Wbt[((long)b * 256 + c) * 256 + h * 32 + dg * 4 + dd] = f2h(acc[dd]);
    __syncthreads();
  }
}

extern "C" void kernel_launch(void* const* d_in, const int* in_sizes, int n_in,
                              void* d_out, int out_size, void* d_ws, size_t ws_size,
                              hipStream_t stream) {
  const void* x      = d_in[0];
  const void* dwk    = d_in[1];
  const void* dwb    = d_in[2];
  const void* lng    = d_in[3];
  const void* lnb    = d_in[4];
  const void* qkv_w  = d_in[5];
  const void* proj_w = d_in[6];
  const void* proj_b = d_in[7];
  const void* bn_g   = d_in[8];
  const void* bn_b   = d_in[9];
  const void* bn_m   = d_in[10];
  const void* bn_v   = d_in[11];
  const void* fc1_w  = d_in[12];
  const void* fc1_b  = d_in[13];
  const void* fc2_w  = d_in[14];
  const void* fc2_b  = d_in[15];
  char* ws = (char*)d_ws;

  int*   flagp   = (int*)  (ws + 0);
  u16*   wqkvT   = (u16*)  (ws + 256);
  u16*   wfc1T   = (u16*)  (ws + 393472);
  u16*   wfc2T   = (u16*)  (ws + 917760);
  float* A_part  = (float*)(ws + 1442048);
  u16*   Wbt     = (u16*)  (ws + 5112064);
  u16*   vbuf    = (u16*)  (ws + 7209216);
  u16*   dwc     = (u16*)  (ws + 32899328);
  u16*   qk_half = (u16*)  (ws + 58589440);
  u16*   h1c     = (u16*)  (ws + 58589440);
  u16*   norm1   = (u16*)d_out;  // fp16-bit scratch; dead before fc2 writes out

  detect_kernel<<<1, 256, 0, stream>>>((const u16*)x, flagp);

  transpose_cvt_kernel<<<2816, 256, 0, stream>>>(qkv_w, wqkvT, fc1_w, wfc1T,
                                                 fc2_w, wfc2T, flagp);

  dwconv_ln_kernel<<<12544, 256, 0, stream>>>(x, dwk, dwb, lng, lnb, dwc, norm1, flagp);

  for (int half = 0; half < 2; ++half) {
    const u16* nh = norm1 + (long)half * 25088 * 256;
    // qk_half (cols 0..511) + vbuf half (cols 512..767) in one launch
    gemm_kernel<128, 2, 2, 5, 256><<<dim3(6, 196, 1), 256, 0, stream>>>(
        nh, wqkvT, qk_half, 256, 256, 512, 0, 0, 0, (long)half * 25088 * 256,
        nullptr, vbuf, nullptr, nullptr, nullptr, nullptr, flagp);
    attn_accum_kernel<<<dim3(64, SPLITN), 256, 0, stream>>>(qk_half, A_part, half * 64);
  }

  softmax_kernel<<<128, 1024, 0, stream>>>(A_part);
  wb_kernel<<<dim3(16, 8), 256, 0, stream>>>(A_part, proj_w, Wbt, flagp);

  gemm_kernel<64, 1, 4, 2, 256><<<dim3(2, 49, 16), 256, 0, stream>>>(
      vbuf, Wbt, dwc, 256, 256, 256,
      (long)3136 * 256, 65536, (long)3136 * 256, 0,
      proj_b, dwc, bn_g, bn_b, bn_m, bn_v, flagp);

  for (int c2 = 0; c2 < 4; ++c2) {
    const long ro = (long)c2 * 12544 * 256;
    gemm_kernel<128, 2, 2, 3, 256><<<dim3(8, 98, 1), 256, 0, stream>>>(
        dwc + ro, wfc1T, h1c, 256, 256, 1024, 0, 0, 0, 0,
        fc1_b, nullptr, nullptr, nullptr, nullptr, nullptr, flagp);
    gemm_kernel<64, 1, 4, 4, 1024><<<dim3(2, 196, 1), 256, 0, stream>>>(
        h1c, wfc2T, d_out, 1024, 1024, 256, 0, 0, 0, ro,
        fc2_b, x, nullptr, nullptr, nullptr, nullptr, flagp);
  }
}

// Round 6
// 532.349 us; speedup vs baseline: 1.5854x; 1.0628x over previous
//
#include <hip/hip_runtime.h>
#include <cstdint>

typedef unsigned short u16;
typedef __attribute__((ext_vector_type(8))) _Float16 f16x8;
typedef __attribute__((ext_vector_type(8))) unsigned short u16x8;
typedef __attribute__((ext_vector_type(4))) float f32x4;

#define SPLITN 7

__device__ __forceinline__ float b2f(u16 u) {
  union { unsigned int i; float f; } v; v.i = ((unsigned int)u) << 16; return v.f;
}
__device__ __forceinline__ u16 f2b(float f) {
  union { float f; unsigned int i; } v; v.f = f;
  unsigned int x = v.i;
  return (u16)((x + 0x7fffu + ((x >> 16) & 1u)) >> 16);
}
__device__ __forceinline__ u16 f2h(float f) {
  union { _Float16 h; u16 u; } v; v.h = (_Float16)f; return v.u;
}
__device__ __forceinline__ float h2f(u16 u) {
  union { u16 u; _Float16 h; } v; v.u = u; return (float)v.h;
}
__device__ __forceinline__ float ld(const void* p, long i, int f) {
  return f ? ((const float*)p)[i] : b2f(((const u16*)p)[i]);
}
template<int F>
__device__ __forceinline__ float4 ld4(const void* p, long i) {
  if (F) return *(const float4*)((const float*)p + i);
  const ushort4 u = *(const ushort4*)((const u16*)p + i);
  return make_float4(b2f(u.x), b2f(u.y), b2f(u.z), b2f(u.w));
}
__device__ __forceinline__ void fma4(float4& a, const float4 x, const float4 k) {
  a.x += x.x * k.x; a.y += x.y * k.y; a.z += x.z * k.z; a.w += x.w * k.w;
}
// tanh-form gelu (max dev from exact erf-gelu ~3e-3, far below threshold)
__device__ __forceinline__ float gelu(float v) {
  const float u = v * (0.7978845608028654f + 0.035677408136300125f * v * v);
  const float e = __expf(2.0f * u);
  return 0.5f * v * (1.0f + (1.0f - 2.0f / (e + 1.0f)));
}

// Kd: dtype sniffer (parallel). flag=1 -> inputs/output are float32.
__global__ __launch_bounds__(256) void detect_kernel(const u16* __restrict__ x,
                                                     int* __restrict__ flag) {
  __shared__ int sbad;
  if (threadIdx.x == 0) sbad = 0;
  __syncthreads();
  int b = 0;
  #pragma unroll
  for (int rr = 0; rr < 2; ++rr) {
    const int i = rr * 256 + threadIdx.x;
    const float v = fabsf(b2f(x[2 * i]));
    if (!(v < 100.f) || v < 1e-6f) ++b;
  }
  atomicAdd(&sbad, b);
  __syncthreads();
  if (threadIdx.x == 0) *flag = (sbad > 16) ? 1 : 0;
}

// K0: all three weight transposes in one dispatch. [R][C] -> fp16 [C][R].
__global__ void transpose_cvt_kernel(const void* __restrict__ w0, u16* __restrict__ o0,
                                     const void* __restrict__ w1, u16* __restrict__ o1,
                                     const void* __restrict__ w2, u16* __restrict__ o2,
                                     const int* __restrict__ flagp) {
  const int f = *flagp;
  int bb = blockIdx.x;
  const void* in; u16* out; int R, C;
  if (bb < 768)       { in = w0; out = o0; R = 256;  C = 768;  }
  else if (bb < 1792) { in = w1; out = o1; R = 256;  C = 1024; bb -= 768; }
  else                { in = w2; out = o2; R = 1024; C = 256;  bb -= 1792; }
  const int o = bb * 256 + threadIdx.x;
  if (o < R * C) {
    const int i = o / R, j = o % R;
    out[o] = f2h(ld(in, (long)j * C + i, f));
  }
}

// ---------------------------------------------------------------------------
// K1 v3: wave per 4-token row group. Conv lanes load 6 x-vectors per conv row
// (shared across the 4 tokens) instead of 4x9. Zero LDS, zero barriers.
template<int F>
__device__ __forceinline__ void dwconv_body4(
    const void* __restrict__ x, const void* __restrict__ dwk, const void* __restrict__ dwb,
    const void* __restrict__ lng, const void* __restrict__ lnb,
    u16* __restrict__ dwc, u16* __restrict__ norm1, int tg, int lane)
{
  const int b = tg / 784, rem = tg % 784;
  const int hh = rem / 14, wg = (rem % 14) * 4;
  const int c0 = lane * 4;
  const long tok0 = (long)b * 3136 + hh * 56 + wg;
  float4 acc[4];
  float4 pv[4];
  if (lane >= 16) {
    const int j0 = c0 - 64;
    const float4 bb = ld4<F>(dwb, j0);
    acc[0] = bb; acc[1] = bb; acc[2] = bb; acc[3] = bb;
    #pragma unroll
    for (int dh = -1; dh <= 1; ++dh) {
      const int h2 = hh + dh;
      if (h2 < 0 || h2 >= 56) continue;
      const long rb = ((long)b * 3136 + h2 * 56) * 256;
      float4 xr[6];
      #pragma unroll
      for (int i = 0; i < 6; ++i) {
        const int w2 = wg - 1 + i;
        xr[i] = (w2 >= 0 && w2 < 56) ? ld4<F>(x, rb + (long)w2 * 256 + c0)
                                     : make_float4(0.f, 0.f, 0.f, 0.f);
      }
      float4 kw[3];
      #pragma unroll
      for (int i = 0; i < 3; ++i)
        kw[i] = ld4<F>(dwk, (long)((dh + 1) * 3 + i) * 192 + j0);
      #pragma unroll
      for (int t = 0; t < 4; ++t)
        #pragma unroll
        for (int i = 0; i < 3; ++i)
          fma4(acc[t], xr[t + i], kw[i]);
    }
  } else {
    #pragma unroll
    for (int t = 0; t < 4; ++t)
      pv[t] = ld4<F>(x, (tok0 + t) * 256 + c0);
  }
  const float4 g = ld4<F>(lng, c0);
  const float4 be = ld4<F>(lnb, c0);
  #pragma unroll
  for (int t = 0; t < 4; ++t) {
    float sx = acc[t].x, sy = acc[t].y, sz = acc[t].z, sw = acc[t].w;
    const float t1x = __shfl(sx, lane - 16), t1y = __shfl(sy, lane - 16),
                t1z = __shfl(sz, lane - 16), t1w = __shfl(sw, lane - 16);
    const float t2x = __shfl(sx, lane - 32), t2y = __shfl(sy, lane - 32),
                t2z = __shfl(sz, lane - 32), t2w = __shfl(sw, lane - 32);
    if (lane >= 32) { sx += t1x; sy += t1y; sz += t1z; sw += t1w; }
    if (lane >= 48) { sx += t2x; sy += t2y; sz += t2z; sw += t2w; }
    float vx, vy, vz, vw;
    if (lane < 16) { vx = pv[t].x; vy = pv[t].y; vz = pv[t].z; vw = pv[t].w; }
    else           { vx = sx;      vy = sy;      vz = sz;      vw = sw;      }
    float sum = vx + vy + vz + vw;
    float sq = vx * vx + vy * vy + vz * vz + vw * vw;
    #pragma unroll
    for (int m = 32; m; m >>= 1) { sum += __shfl_xor(sum, m); sq += __shfl_xor(sq, m); }
    const float mu = sum * (1.0f / 256.0f);
    const float var = sq * (1.0f / 256.0f) - mu * mu;
    const float rstd = rsqrtf(fmaxf(var, 0.f) + 1e-6f);
    ushort4 dv, nv;
    dv.x = f2h(vx); dv.y = f2h(vy); dv.z = f2h(vz); dv.w = f2h(vw);
    nv.x = f2h((vx - mu) * rstd * g.x + be.x);
    nv.y = f2h((vy - mu) * rstd * g.y + be.y);
    nv.z = f2h((vz - mu) * rstd * g.z + be.z);
    nv.w = f2h((vw - mu) * rstd * g.w + be.w);
    *(ushort4*)(dwc + (tok0 + t) * 256 + c0) = dv;
    *(ushort4*)(norm1 + (tok0 + t) * 256 + c0) = nv;
  }
}

__global__ __launch_bounds__(256) void dwconv_ln_kernel(
    const void* __restrict__ x, const void* __restrict__ dwk, const void* __restrict__ dwb,
    const void* __restrict__ lng, const void* __restrict__ lnb,
    u16* __restrict__ dwc, u16* __restrict__ norm1, const int* __restrict__ flagp)
{
  const int wave = threadIdx.x >> 6, lane = threadIdx.x & 63;
  const int tg = blockIdx.x * 4 + wave;
  if (*flagp) dwconv_body4<1>(x, dwk, dwb, lng, lnb, dwc, norm1, tg, lane);
  else        dwconv_body4<0>(x, dwk, dwb, lng, lnb, dwc, norm1, tg, lane);
}

// ---------------------------------------------------------------------------
// Generic fp16 MFMA GEMM. BK=64, global_load_lds staging with XOR granule
// swizzle (granule (row,c) holds global (row, c^(row&7)) -> conflict-free
// ds_read_b128 while keeping the DMA destination contiguous). B transposed.
// EPI: 0 fp16; 2 +bias+aux(fp16)+BN fp16; 3 +bias gelu fp16;
//      4 +bias+residual(input dtype) -> flag dtype; 5 split C qk/v.
template<int BM, int WR, int WC, int EPI, int KT>
__global__ __launch_bounds__(256) void gemm_kernel(
    const u16* __restrict__ A, const u16* __restrict__ Bt, void* C,
    int lda, int ldb, int ldc,
    long aZ, long bZ, long cZ, long zoff,
    const void* __restrict__ bias, const void* aux,
    const void* __restrict__ bng, const void* __restrict__ bnb,
    const void* __restrict__ bnm, const void* __restrict__ bnv,
    const int* __restrict__ flagp)
{
  static_assert(BM == 64 || BM == 128, "");
  constexpr int BN = 128;
  constexpr int WM = BM / WR, WN = BN / WC;
  constexpr int MI = WM / 16, NI = WN / 16;
  __shared__ __align__(16) u16 As[BM * 64];
  __shared__ __align__(16) u16 Bs[BN * 64];
  const int f = (EPI == 0 || EPI == 5) ? 0 : *flagp;
  const int tid = threadIdx.x;
  const int wave = tid >> 6, lane = tid & 63;
  const int wr = wave / WC, wc = wave % WC;
  const int quad = lane >> 4, l16 = lane & 15;
  const int tileM = blockIdx.y * BM, tileN = blockIdx.x * BN;
  const u16* Ab = A + (long)blockIdx.z * aZ + (long)tileM * lda;
  const u16* Bb = Bt + (long)blockIdx.z * bZ + (long)tileN * ldb;
  f32x4 acc[MI][NI];
  #pragma unroll
  for (int mi = 0; mi < MI; ++mi)
    #pragma unroll
    for (int ni = 0; ni < NI; ++ni)
      acc[mi][ni] = (f32x4){0.f, 0.f, 0.f, 0.f};

  for (int k0 = 0; k0 < KT; k0 += 64) {
    #pragma unroll
    for (int r = 0; r < BM / 32; ++r) {
      const int fg = r * 256 + tid;          // granule id (16B each)
      const int row = fg >> 3, cs = (fg & 7) ^ (row & 7);
      const u16* g = Ab + (long)row * lda + k0 + cs * 8;
      __builtin_amdgcn_global_load_lds(
          (const __attribute__((address_space(1))) void*)g,
          (__attribute__((address_space(3))) void*)(As + (r * 256 + wave * 64) * 8),
          16, 0, 0);
    }
    #pragma unroll
    for (int r = 0; r < 4; ++r) {
      const int fg = r * 256 + tid;
      const int row = fg >> 3, cs = (fg & 7) ^ (row & 7);
      const u16* g = Bb + (long)row * ldb + k0 + cs * 8;
      __builtin_amdgcn_global_load_lds(
          (const __attribute__((address_space(1))) void*)g,
          (__attribute__((address_space(3))) void*)(Bs + (r * 256 + wave * 64) * 8),
          16, 0, 0);
    }
    __syncthreads();
    #pragma unroll
    for (int ks = 0; ks < 2; ++ks) {
      f16x8 af[MI], bfr[NI];
      #pragma unroll
      for (int mi = 0; mi < MI; ++mi) {
        const int R = wr * WM + mi * 16 + l16;
        const int kc = ks * 4 + quad;
        af[mi] = *(const f16x8*)&As[(R * 8 + (kc ^ (R & 7))) * 8];
      }
      #pragma unroll
      for (int ni = 0; ni < NI; ++ni) {
        const int S = wc * WN + ni * 16 + l16;
        const int kc = ks * 4 + quad;
        bfr[ni] = *(const f16x8*)&Bs[(S * 8 + (kc ^ (S & 7))) * 8];
      }
      #pragma unroll
      for (int mi = 0; mi < MI; ++mi)
        #pragma unroll
        for (int ni = 0; ni < NI; ++ni)
          acc[mi][ni] = __builtin_amdgcn_mfma_f32_16x16x32_f16(af[mi], bfr[ni], acc[mi][ni], 0, 0, 0);
    }
    __syncthreads();
  }

  const long zC = (long)blockIdx.z * cZ + ((EPI == 5) ? 0 : zoff);
  #pragma unroll
  for (int mi = 0; mi < MI; ++mi) {
    #pragma unroll
    for (int ni = 0; ni < NI; ++ni) {
      const int col = tileN + wc * WN + ni * 16 + l16;
      #pragma unroll
      for (int r = 0; r < 4; ++r) {
        const int row = tileM + wr * WM + mi * 16 + quad * 4 + r;
        const long ci = zC + (long)row * ldc + col;
        float v = acc[mi][ni][r];
        if (EPI == 0) {
          ((u16*)C)[ci] = f2h(v);
        } else if (EPI == 2) {
          v += ld(bias, col, f);
          v += h2f(((const u16*)aux)[ci]);
          v = (v - ld(bnm, col, f)) * rsqrtf(ld(bnv, col, f) + 1e-3f) * ld(bng, col, f) + ld(bnb, col, f);
          ((u16*)C)[ci] = f2h(v);
        } else if (EPI == 3) {
          v += ld(bias, col, f);
          ((u16*)C)[ci] = f2h(gelu(v));
        } else if (EPI == 4) {
          v += ld(bias, col, f);
          v += ld(aux, ci, f);
          if (f) ((float*)C)[ci] = v; else ((u16*)C)[ci] = f2b(v);
        } else {  // EPI == 5: qk (cols 0..511) / v (cols 512..767) split
          if (col < 512) ((u16*)C)[(long)row * 512 + col] = f2h(v);
          else ((u16*)aux)[zoff + (long)row * 256 + (col - 512)] = f2h(v);
        }
      }
    }
  }
}

// ---------------------------------------------------------------------------
// K3: MFMA attention accumulation (unchanged from R5 — was ~10 µs).
__global__ __launch_bounds__(256) void attn_accum_kernel(
    const u16* __restrict__ qk, float* __restrict__ A_part, int pair0)
{
  const int pl = blockIdx.x;
  const int split = blockIdx.y;
  const int bl = pl >> 3, h = pl & 7;
  const int tid = threadIdx.x;
  const int wave = tid >> 6, lane = tid & 63;
  const int quad = lane >> 4, l16 = lane & 15;
  const int dq = wave >> 1, eq = wave & 1;
  __shared__ __align__(16) u16 lqT[32 * 72];
  __shared__ __align__(16) u16 lkT[32 * 72];
  const long rowbase = (long)bl * 3136 * 512;
  const int n0 = split * 448;
  f32x4 acc = (f32x4){0.f, 0.f, 0.f, 0.f};
  const int seg = tid & 7;

  for (int ch = 0; ch < 7; ++ch) {
    const int nb = n0 + ch * 64;
    #pragma unroll
    for (int rr = 0; rr < 2; ++rr) {
      const int a = rr * 256 + tid;
      const int nl = a >> 3;
      const int co = (seg < 4) ? h * 32 + seg * 8 : 256 + h * 32 + (seg - 4) * 8;
      const u16x8 v8 = *(const u16x8*)(qk + rowbase + (long)(nb + nl) * 512 + co);
      float vf[8], p = 0.f;
      #pragma unroll
      for (int i = 0; i < 8; ++i) { vf[i] = h2f(v8[i]); p += vf[i] * vf[i]; }
      float p1 = p + __shfl_xor(p, 1);
      float p2 = p1 + __shfl_xor(p1, 2);
      const float other = __shfl_xor(p2, 4);
      const float ssq = (seg < 4) ? p2 : other;
      const float ssk = (seg < 4) ? other : p2;
      const float s = 0.17677669529663687f * rsqrtf(fmaxf(ssq, 1e-12f)) *
                      rsqrtf(fmaxf(ssk, 1e-12f));
      if (seg < 4) {
        const int db = seg * 8;
        #pragma unroll
        for (int i = 0; i < 8; ++i) {
          const int d = db + i;
          lqT[d * 72 + (nl ^ (d & 24))] = f2h(vf[i] * s);
        }
      } else {
        const int eb = (seg - 4) * 8;
        #pragma unroll
        for (int i = 0; i < 8; ++i) {
          const int e = eb + i;
          lkT[e * 72 + (nl ^ (e & 24))] = v8[i];
        }
      }
    }
    __syncthreads();
    #pragma unroll
    for (int ks = 0; ks < 2; ++ks) {
      const int tb = ks * 32 + quad * 8;
      const int dA = dq * 16 + l16;
      const int eB = eq * 16 + l16;
      const f16x8 af = *(const f16x8*)&lqT[dA * 72 + (tb ^ (dA & 24))];
      const f16x8 bf = *(const f16x8*)&lkT[eB * 72 + (tb ^ (eB & 24))];
      acc = __builtin_amdgcn_mfma_f32_16x16x32_f16(af, bf, acc, 0, 0, 0);
    }
    __syncthreads();
  }
  float* o = A_part + ((long)(pair0 + pl) * SPLITN + split) * 1024;
  #pragma unroll
  for (int r = 0; r < 4; ++r)
    o[(dq * 16 + quad * 4 + r) * 32 + eq * 16 + l16] = acc[r];
}

__global__ __launch_bounds__(1024) void softmax_kernel(float* A_part) {
  const int pair = blockIdx.x;
  const int t = threadIdx.x;
  float v = 0.f;
  float* base = A_part + (long)pair * SPLITN * 1024 + t;
  #pragma unroll
  for (int s = 0; s < SPLITN; ++s) v += base[s * 1024];
  float mx = v;
  #pragma unroll
  for (int m = 16; m; m >>= 1) mx = fmaxf(mx, __shfl_xor(mx, m, 32));
  const float p = expf(v - mx);
  float sm = p;
  #pragma unroll
  for (int m = 16; m; m >>= 1) sm += __shfl_xor(sm, m, 32);
  base[0] = p / sm;
}

__global__ __launch_bounds__(256) void wb_kernel(
    const float* __restrict__ A_part, const void* __restrict__ proj_w,
    u16* __restrict__ Wbt, const int* __restrict__ flagp)
{
  const int f = *flagp;
  const int b = blockIdx.x;
  const int cs = blockIdx.y;
  const int tid = threadIdx.x;
  const int cg = tid & 31, dg = tid >> 5;
  const int c = cs * 32 + cg;
  __shared__ float Ah[32][32];
  __shared__ float pw[32][33];
  for (int h = 0; h < 8; ++h) {
    const float* Abase = A_part + ((long)(b * 8 + h) * SPLITN) * 1024;
    #pragma unroll
    for (int rr = 0; rr < 4; ++rr) {
      const int ff = rr * 256 + tid;
      Ah[ff >> 5][ff & 31] = Abase[ff];
    }
    #pragma unroll
    for (int rr = 0; rr < 4; ++rr) {
      const int ff = rr * 256 + tid;
      const int e = ff >> 5, ccc = ff & 31;
      pw[e][ccc] = ld(proj_w, (long)(h * 32 + e) * 256 + cs * 32 + ccc, f);
    }
    __syncthreads();
    float acc[4] = {0.f, 0.f, 0.f, 0.f};
    #pragma unroll
    for (int e = 0; e < 32; ++e) {
      const float pv = pw[e][cg];
      #pragma unroll
      for (int dd = 0; dd < 4; ++dd)
        acc[dd] += Ah[dg * 4 + dd][e] * pv;
    }
    #pragma unroll
    for (int dd = 0; dd < 4; ++dd)
      Wbt[((long)b * 256 + c) * 256 + h * 32 + dg * 4 + dd] = f2h(acc[dd]);
    __syncthreads();
  }
}

extern "C" void kernel_launch(void* const* d_in, const int* in_sizes, int n_in,
                              void* d_out, int out_size, void* d_ws, size_t ws_size,
                              hipStream_t stream) {
  const void* x      = d_in[0];
  const void* dwk    = d_in[1];
  const void* dwb    = d_in[2];
  const void* lng    = d_in[3];
  const void* lnb    = d_in[4];
  const void* qkv_w  = d_in[5];
  const void* proj_w = d_in[6];
  const void* proj_b = d_in[7];
  const void* bn_g   = d_in[8];
  const void* bn_b   = d_in[9];
  const void* bn_m   = d_in[10];
  const void* bn_v   = d_in[11];
  const void* fc1_w  = d_in[12];
  const void* fc1_b  = d_in[13];
  const void* fc2_w  = d_in[14];
  const void* fc2_b  = d_in[15];
  char* ws = (char*)d_ws;

  int*   flagp   = (int*)  (ws + 0);
  u16*   wqkvT   = (u16*)  (ws + 256);
  u16*   wfc1T   = (u16*)  (ws + 393472);
  u16*   wfc2T   = (u16*)  (ws + 917760);
  float* A_part  = (float*)(ws + 1442048);
  u16*   Wbt     = (u16*)  (ws + 5112064);
  u16*   vbuf    = (u16*)  (ws + 7209216);
  u16*   dwc     = (u16*)  (ws + 32899328);
  u16*   qk_half = (u16*)  (ws + 58589440);
  u16*   h1c     = (u16*)  (ws + 58589440);
  u16*   norm1   = (u16*)d_out;  // fp16-bit scratch; dead before fc2 writes out

  detect_kernel<<<1, 256, 0, stream>>>((const u16*)x, flagp);

  transpose_cvt_kernel<<<2816, 256, 0, stream>>>(qkv_w, wqkvT, fc1_w, wfc1T,
                                                 fc2_w, wfc2T, flagp);

  dwconv_ln_kernel<<<3136, 256, 0, stream>>>(x, dwk, dwb, lng, lnb, dwc, norm1, flagp);

  for (int half = 0; half < 2; ++half) {
    const u16* nh = norm1 + (long)half * 25088 * 256;
    // qk_half (cols 0..511) + vbuf half (cols 512..767) in one launch
    gemm_kernel<128, 2, 2, 5, 256><<<dim3(6, 196, 1), 256, 0, stream>>>(
        nh, wqkvT, qk_half, 256, 256, 512, 0, 0, 0, (long)half * 25088 * 256,
        nullptr, vbuf, nullptr, nullptr, nullptr, nullptr, flagp);
    attn_accum_kernel<<<dim3(64, SPLITN), 256, 0, stream>>>(qk_half, A_part, half * 64);
  }

  softmax_kernel<<<128, 1024, 0, stream>>>(A_part);
  wb_kernel<<<dim3(16, 8), 256, 0, stream>>>(A_part, proj_w, Wbt, flagp);

  gemm_kernel<64, 1, 4, 2, 256><<<dim3(2, 49, 16), 256, 0, stream>>>(
      vbuf, Wbt, dwc, 256, 256, 256,
      (long)3136 * 256, 65536, (long)3136 * 256, 0,
      proj_b, dwc, bn_g, bn_b, bn_m, bn_v, flagp);

  for (int c2 = 0; c2 < 4; ++c2) {
    const long ro = (long)c2 * 12544 * 256;
    gemm_kernel<128, 2, 2, 3, 256><<<dim3(8, 98, 1), 256, 0, stream>>>(
        dwc + ro, wfc1T, h1c, 256, 256, 1024, 0, 0, 0, 0,
        fc1_b, nullptr, nullptr, nullptr, nullptr, nullptr, flagp);
    gemm_kernel<64, 1, 4, 4, 1024><<<dim3(2, 196, 1), 256, 0, stream>>>(
        h1c, wfc2T, d_out, 1024, 1024, 256, 0, 0, 0, ro,
        fc2_b, x, nullptr, nullptr, nullptr, nullptr, flagp);
  }
}

// Round 7
// 464.101 us; speedup vs baseline: 1.8185x; 1.1471x over previous
//
#include <hip/hip_runtime.h>
#include <cstdint>

typedef unsigned short u16;
typedef __attribute__((ext_vector_type(8))) _Float16 f16x8;
typedef __attribute__((ext_vector_type(8))) unsigned short u16x8;
typedef __attribute__((ext_vector_type(4))) float f32x4;

#define SPLITN 7

__device__ __forceinline__ float b2f(u16 u) {
  union { unsigned int i; float f; } v; v.i = ((unsigned int)u) << 16; return v.f;
}
__device__ __forceinline__ u16 f2b(float f) {
  union { float f; unsigned int i; } v; v.f = f;
  unsigned int x = v.i;
  return (u16)((x + 0x7fffu + ((x >> 16) & 1u)) >> 16);
}
__device__ __forceinline__ u16 f2h(float f) {
  union { _Float16 h; u16 u; } v; v.h = (_Float16)f; return v.u;
}
__device__ __forceinline__ float h2f(u16 u) {
  union { u16 u; _Float16 h; } v; v.u = u; return (float)v.h;
}
__device__ __forceinline__ float ld(const void* p, long i, int f) {
  return f ? ((const float*)p)[i] : b2f(((const u16*)p)[i]);
}
template<int F>
__device__ __forceinline__ float4 ld4(const void* p, long i) {
  if (F) return *(const float4*)((const float*)p + i);
  const ushort4 u = *(const ushort4*)((const u16*)p + i);
  return make_float4(b2f(u.x), b2f(u.y), b2f(u.z), b2f(u.w));
}
__device__ __forceinline__ void fma4(float4& a, const float4 x, const float4 k) {
  a.x += x.x * k.x; a.y += x.y * k.y; a.z += x.z * k.z; a.w += x.w * k.w;
}
// tanh-form gelu (max dev from exact erf-gelu ~3e-3, far below threshold)
__device__ __forceinline__ float gelu(float v) {
  const float u = v * (0.7978845608028654f + 0.035677408136300125f * v * v);
  const float e = __expf(2.0f * u);
  return 0.5f * v * (1.0f + (1.0f - 2.0f / (e + 1.0f)));
}
#define GLDS(gp, lp) __builtin_amdgcn_global_load_lds( \
    (const __attribute__((address_space(1))) void*)(gp), \
    (__attribute__((address_space(3))) void*)(lp), 16, 0, 0)

// Kd: dtype sniffer (parallel). flag=1 -> inputs/output are float32.
__global__ __launch_bounds__(256) void detect_kernel(const u16* __restrict__ x,
                                                     int* __restrict__ flag) {
  __shared__ int sbad;
  if (threadIdx.x == 0) sbad = 0;
  __syncthreads();
  int b = 0;
  #pragma unroll
  for (int rr = 0; rr < 2; ++rr) {
    const int i = rr * 256 + threadIdx.x;
    const float v = fabsf(b2f(x[2 * i]));
    if (!(v < 100.f) || v < 1e-6f) ++b;
  }
  atomicAdd(&sbad, b);
  __syncthreads();
  if (threadIdx.x == 0) *flag = (sbad > 16) ? 1 : 0;
}

// K0: all three weight transposes in one dispatch. [R][C] -> fp16 [C][R].
__global__ void transpose_cvt_kernel(const void* __restrict__ w0, u16* __restrict__ o0,
                                     const void* __restrict__ w1, u16* __restrict__ o1,
                                     const void* __restrict__ w2, u16* __restrict__ o2,
                                     const int* __restrict__ flagp) {
  const int f = *flagp;
  int bb = blockIdx.x;
  const void* in; u16* out; int R, C;
  if (bb < 768)       { in = w0; out = o0; R = 256;  C = 768;  }
  else if (bb < 1792) { in = w1; out = o1; R = 256;  C = 1024; bb -= 768; }
  else                { in = w2; out = o2; R = 1024; C = 256;  bb -= 1792; }
  const int o = bb * 256 + threadIdx.x;
  if (o < R * C) {
    const int i = o / R, j = o % R;
    out[o] = f2h(ld(in, (long)j * C + i, f));
  }
}

// ---------------------------------------------------------------------------
// K1: wave per 4-token row group dwconv + group cumsum + LN (unchanged).
template<int F>
__device__ __forceinline__ void dwconv_body4(
    const void* __restrict__ x, const void* __restrict__ dwk, const void* __restrict__ dwb,
    const void* __restrict__ lng, const void* __restrict__ lnb,
    u16* __restrict__ dwc, u16* __restrict__ norm1, int tg, int lane)
{
  const int b = tg / 784, rem = tg % 784;
  const int hh = rem / 14, wg = (rem % 14) * 4;
  const int c0 = lane * 4;
  const long tok0 = (long)b * 3136 + hh * 56 + wg;
  float4 acc[4];
  float4 pv[4];
  if (lane >= 16) {
    const int j0 = c0 - 64;
    const float4 bb = ld4<F>(dwb, j0);
    acc[0] = bb; acc[1] = bb; acc[2] = bb; acc[3] = bb;
    #pragma unroll
    for (int dh = -1; dh <= 1; ++dh) {
      const int h2 = hh + dh;
      if (h2 < 0 || h2 >= 56) continue;
      const long rb = ((long)b * 3136 + h2 * 56) * 256;
      float4 xr[6];
      #pragma unroll
      for (int i = 0; i < 6; ++i) {
        const int w2 = wg - 1 + i;
        xr[i] = (w2 >= 0 && w2 < 56) ? ld4<F>(x, rb + (long)w2 * 256 + c0)
                                     : make_float4(0.f, 0.f, 0.f, 0.f);
      }
      float4 kw[3];
      #pragma unroll
      for (int i = 0; i < 3; ++i)
        kw[i] = ld4<F>(dwk, (long)((dh + 1) * 3 + i) * 192 + j0);
      #pragma unroll
      for (int t = 0; t < 4; ++t)
        #pragma unroll
        for (int i = 0; i < 3; ++i)
          fma4(acc[t], xr[t + i], kw[i]);
    }
  } else {
    #pragma unroll
    for (int t = 0; t < 4; ++t)
      pv[t] = ld4<F>(x, (tok0 + t) * 256 + c0);
  }
  const float4 g = ld4<F>(lng, c0);
  const float4 be = ld4<F>(lnb, c0);
  #pragma unroll
  for (int t = 0; t < 4; ++t) {
    float sx = acc[t].x, sy = acc[t].y, sz = acc[t].z, sw = acc[t].w;
    const float t1x = __shfl(sx, lane - 16), t1y = __shfl(sy, lane - 16),
                t1z = __shfl(sz, lane - 16), t1w = __shfl(sw, lane - 16);
    const float t2x = __shfl(sx, lane - 32), t2y = __shfl(sy, lane - 32),
                t2z = __shfl(sz, lane - 32), t2w = __shfl(sw, lane - 32);
    if (lane >= 32) { sx += t1x; sy += t1y; sz += t1z; sw += t1w; }
    if (lane >= 48) { sx += t2x; sy += t2y; sz += t2z; sw += t2w; }
    float vx, vy, vz, vw;
    if (lane < 16) { vx = pv[t].x; vy = pv[t].y; vz = pv[t].z; vw = pv[t].w; }
    else           { vx = sx;      vy = sy;      vz = sz;      vw = sw;      }
    float sum = vx + vy + vz + vw;
    float sq = vx * vx + vy * vy + vz * vz + vw * vw;
    #pragma unroll
    for (int m = 32; m; m >>= 1) { sum += __shfl_xor(sum, m); sq += __shfl_xor(sq, m); }
    const float mu = sum * (1.0f / 256.0f);
    const float var = sq * (1.0f / 256.0f) - mu * mu;
    const float rstd = rsqrtf(fmaxf(var, 0.f) + 1e-6f);
    ushort4 dv, nv;
    dv.x = f2h(vx); dv.y = f2h(vy); dv.z = f2h(vz); dv.w = f2h(vw);
    nv.x = f2h((vx - mu) * rstd * g.x + be.x);
    nv.y = f2h((vy - mu) * rstd * g.y + be.y);
    nv.z = f2h((vz - mu) * rstd * g.z + be.z);
    nv.w = f2h((vw - mu) * rstd * g.w + be.w);
    *(ushort4*)(dwc + (tok0 + t) * 256 + c0) = dv;
    *(ushort4*)(norm1 + (tok0 + t) * 256 + c0) = nv;
  }
}

__global__ __launch_bounds__(256) void dwconv_ln_kernel(
    const void* __restrict__ x, const void* __restrict__ dwk, const void* __restrict__ dwb,
    const void* __restrict__ lng, const void* __restrict__ lnb,
    u16* __restrict__ dwc, u16* __restrict__ norm1, const int* __restrict__ flagp)
{
  const int wave = threadIdx.x >> 6, lane = threadIdx.x & 63;
  const int tg = blockIdx.x * 4 + wave;
  if (*flagp) dwconv_body4<1>(x, dwk, dwb, lng, lnb, dwc, norm1, tg, lane);
  else        dwconv_body4<0>(x, dwk, dwb, lng, lnb, dwc, norm1, tg, lane);
}

// ---------------------------------------------------------------------------
// Generic fp16 MFMA GEMM (qkv EPI5, merged EPI2). BK=64, XOR-swizzled staging.
template<int BM, int WR, int WC, int EPI, int KT>
__global__ __launch_bounds__(256) void gemm_kernel(
    const u16* __restrict__ A, const u16* __restrict__ Bt, void* C,
    int lda, int ldb, int ldc,
    long aZ, long bZ, long cZ, long zoff,
    const void* __restrict__ bias, const void* aux,
    const void* __restrict__ bng, const void* __restrict__ bnb,
    const void* __restrict__ bnm, const void* __restrict__ bnv,
    const int* __restrict__ flagp)
{
  static_assert(BM == 64 || BM == 128, "");
  constexpr int BN = 128;
  constexpr int WM = BM / WR, WN = BN / WC;
  constexpr int MI = WM / 16, NI = WN / 16;
  __shared__ __align__(16) u16 As[BM * 64];
  __shared__ __align__(16) u16 Bs[BN * 64];
  const int f = (EPI == 0 || EPI == 5) ? 0 : *flagp;
  const int tid = threadIdx.x;
  const int wave = tid >> 6, lane = tid & 63;
  const int wr = wave / WC, wc = wave % WC;
  const int quad = lane >> 4, l16 = lane & 15;
  const int tileM = blockIdx.y * BM, tileN = blockIdx.x * BN;
  const u16* Ab = A + (long)blockIdx.z * aZ + (long)tileM * lda;
  const u16* Bb = Bt + (long)blockIdx.z * bZ + (long)tileN * ldb;
  f32x4 acc[MI][NI];
  #pragma unroll
  for (int mi = 0; mi < MI; ++mi)
    #pragma unroll
    for (int ni = 0; ni < NI; ++ni)
      acc[mi][ni] = (f32x4){0.f, 0.f, 0.f, 0.f};

  for (int k0 = 0; k0 < KT; k0 += 64) {
    #pragma unroll
    for (int r = 0; r < BM / 32; ++r) {
      const int fg = r * 256 + tid;
      const int row = fg >> 3, cs = (fg & 7) ^ (row & 7);
      GLDS(Ab + (long)row * lda + k0 + cs * 8, As + (r * 256 + wave * 64) * 8);
    }
    #pragma unroll
    for (int r = 0; r < 4; ++r) {
      const int fg = r * 256 + tid;
      const int row = fg >> 3, cs = (fg & 7) ^ (row & 7);
      GLDS(Bb + (long)row * ldb + k0 + cs * 8, Bs + (r * 256 + wave * 64) * 8);
    }
    __syncthreads();
    #pragma unroll
    for (int ks = 0; ks < 2; ++ks) {
      f16x8 af[MI], bfr[NI];
      #pragma unroll
      for (int mi = 0; mi < MI; ++mi) {
        const int R = wr * WM + mi * 16 + l16;
        const int kc = ks * 4 + quad;
        af[mi] = *(const f16x8*)&As[(R * 8 + (kc ^ (R & 7))) * 8];
      }
      #pragma unroll
      for (int ni = 0; ni < NI; ++ni) {
        const int S = wc * WN + ni * 16 + l16;
        const int kc = ks * 4 + quad;
        bfr[ni] = *(const f16x8*)&Bs[(S * 8 + (kc ^ (S & 7))) * 8];
      }
      #pragma unroll
      for (int mi = 0; mi < MI; ++mi)
        #pragma unroll
        for (int ni = 0; ni < NI; ++ni)
          acc[mi][ni] = __builtin_amdgcn_mfma_f32_16x16x32_f16(af[mi], bfr[ni], acc[mi][ni], 0, 0, 0);
    }
    __syncthreads();
  }

  const long zC = (long)blockIdx.z * cZ + ((EPI == 5) ? 0 : zoff);
  #pragma unroll
  for (int mi = 0; mi < MI; ++mi) {
    #pragma unroll
    for (int ni = 0; ni < NI; ++ni) {
      const int col = tileN + wc * WN + ni * 16 + l16;
      #pragma unroll
      for (int r = 0; r < 4; ++r) {
        const int row = tileM + wr * WM + mi * 16 + quad * 4 + r;
        const long ci = zC + (long)row * ldc + col;
        float v = acc[mi][ni][r];
        if (EPI == 2) {
          v += ld(bias, col, f);
          v += h2f(((const u16*)aux)[ci]);
          v = (v - ld(bnm, col, f)) * rsqrtf(ld(bnv, col, f) + 1e-3f) * ld(bng, col, f) + ld(bnb, col, f);
          ((u16*)C)[ci] = f2h(v);
        } else {  // EPI == 5: qk (cols 0..511) / v (cols 512..767) split
          if (col < 512) ((u16*)C)[(long)row * 512 + col] = f2h(v);
          else ((u16*)aux)[zoff + (long)row * 256 + (col - 512)] = f2h(v);
        }
      }
    }
  }
}

// ---------------------------------------------------------------------------
// K-MLP: fused fc1+gelu+fc2+bias+residual megakernel. One block = 64 tokens.
// dwc tile staged once (LDS, swizzled); 8 h-chunks of 128: fc1 (K=256,
// streamed W1 slices) -> gelu -> Hs (LDS) -> fc2 partial (K=128, streamed W2
// slices) into persistent 64x256 f32 accumulators. h1 never touches HBM.
// LDS 80 KB -> 2 blocks/CU.
__global__ __launch_bounds__(256, 2) void mlp_kernel(
    const u16* __restrict__ dwc, const u16* __restrict__ w1t, const u16* __restrict__ w2t,
    const void* __restrict__ b1, const void* __restrict__ b2,
    const void* __restrict__ x, void* __restrict__ out,
    const int* __restrict__ flagp)
{
  __shared__ __align__(16) u16 Ds[64 * 256];   // 32 KB: dwc tile, K=256 (32 granules/row)
  __shared__ __align__(16) u16 Hs[64 * 128];   // 16 KB: h chunk (16 granules/row)
  __shared__ __align__(16) u16 Bs[256 * 64];   // 32 KB: streamed B tile (8 granules/row)
  const int f = *flagp;
  const int tid = threadIdx.x;
  const int wave = tid >> 6, lane = tid & 63;
  const int quad = lane >> 4, l16 = lane & 15;
  const int tileM = blockIdx.x * 64;

  // stage Ds once: 2048 granules, global (row, c^(row&7)) -> LDS (row, c)
  #pragma unroll
  for (int r = 0; r < 8; ++r) {
    const int fg = r * 256 + tid;
    const int row = fg >> 5, cs = (fg & 31) ^ (row & 7);
    GLDS(dwc + (long)(tileM + row) * 256 + cs * 8, Ds + (r * 256 + wave * 64) * 8);
  }

  f32x4 accO[4][4];
  #pragma unroll
  for (int mi = 0; mi < 4; ++mi)
    #pragma unroll
    for (int ni = 0; ni < 4; ++ni)
      accO[mi][ni] = (f32x4){0.f, 0.f, 0.f, 0.f};

  for (int hc = 0; hc < 8; ++hc) {
    // ---- fc1: h[64x128] = Ds[64x256] @ W1[256 x 128-chunk] ----
    f32x4 acc1[4][2];
    #pragma unroll
    for (int mi = 0; mi < 4; ++mi)
      #pragma unroll
      for (int ni = 0; ni < 2; ++ni)
        acc1[mi][ni] = (f32x4){0.f, 0.f, 0.f, 0.f};

    for (int it = 0; it < 4; ++it) {
      #pragma unroll
      for (int r = 0; r < 4; ++r) {  // Bs: 128 rows x 8 granules
        const int fg = r * 256 + tid;
        const int row = fg >> 3, cs = (fg & 7) ^ (row & 7);
        GLDS(w1t + (long)(hc * 128 + row) * 256 + it * 64 + cs * 8,
             Bs + (r * 256 + wave * 64) * 8);
      }
      __syncthreads();
      #pragma unroll
      for (int ks = 0; ks < 2; ++ks) {
        const int kc = it * 8 + ks * 4 + quad;  // Ds k-granule 0..31
        const int kl = ks * 4 + quad;           // Bs-local 0..7
        f16x8 af[4], bf[2];
        #pragma unroll
        for (int mi = 0; mi < 4; ++mi) {
          const int R = mi * 16 + l16;
          af[mi] = *(const f16x8*)&Ds[(R * 32 + (kc ^ (R & 7))) * 8];
        }
        #pragma unroll
        for (int ni = 0; ni < 2; ++ni) {
          const int S = wave * 32 + ni * 16 + l16;
          bf[ni] = *(const f16x8*)&Bs[(S * 8 + (kl ^ (S & 7))) * 8];
        }
        #pragma unroll
        for (int mi = 0; mi < 4; ++mi)
          #pragma unroll
          for (int ni = 0; ni < 2; ++ni)
            acc1[mi][ni] = __builtin_amdgcn_mfma_f32_16x16x32_f16(af[mi], bf[ni], acc1[mi][ni], 0, 0, 0);
      }
      __syncthreads();
    }
    // ---- gelu -> Hs (swizzled granules) ----
    #pragma unroll
    for (int mi = 0; mi < 4; ++mi)
      #pragma unroll
      for (int ni = 0; ni < 2; ++ni)
        #pragma unroll
        for (int r = 0; r < 4; ++r) {
          const int row = mi * 16 + quad * 4 + r;
          const int col = wave * 32 + ni * 16 + l16;
          const float v = acc1[mi][ni][r] + ld(b1, hc * 128 + col, f);
          Hs[(row * 16 + ((col >> 3) ^ (row & 7))) * 8 + (col & 7)] = f2h(gelu(v));
        }
    __syncthreads();
    // ---- fc2 partial: accO += Hs[64x128] @ W2[128-chunk x 256] ----
    for (int it2 = 0; it2 < 2; ++it2) {
      #pragma unroll
      for (int r = 0; r < 8; ++r) {  // Bs: 256 rows x 8 granules
        const int fg = r * 256 + tid;
        const int row = fg >> 3, cs = (fg & 7) ^ (row & 7);
        GLDS(w2t + (long)row * 1024 + hc * 128 + it2 * 64 + cs * 8,
             Bs + (r * 256 + wave * 64) * 8);
      }
      __syncthreads();
      #pragma unroll
      for (int ks = 0; ks < 2; ++ks) {
        const int kc = it2 * 8 + ks * 4 + quad;  // Hs k-granule 0..15
        const int kl = ks * 4 + quad;
        f16x8 af[4], bf[4];
        #pragma unroll
        for (int mi = 0; mi < 4; ++mi) {
          const int R = mi * 16 + l16;
          af[mi] = *(const f16x8*)&Hs[(R * 16 + (kc ^ (R & 7))) * 8];
        }
        #pragma unroll
        for (int ni = 0; ni < 4; ++ni) {
          const int S = wave * 64 + ni * 16 + l16;
          bf[ni] = *(const f16x8*)&Bs[(S * 8 + (kl ^ (S & 7))) * 8];
        }
        #pragma unroll
        for (int mi = 0; mi < 4; ++mi)
          #pragma unroll
          for (int ni = 0; ni < 4; ++ni)
            accO[mi][ni] = __builtin_amdgcn_mfma_f32_16x16x32_f16(af[mi], bf[ni], accO[mi][ni], 0, 0, 0);
      }
      __syncthreads();
    }
  }
  // ---- epilogue: out = accO + b2 + x ----
  #pragma unroll
  for (int mi = 0; mi < 4; ++mi)
    #pragma unroll
    for (int ni = 0; ni < 4; ++ni) {
      const int col = wave * 64 + ni * 16 + l16;
      #pragma unroll
      for (int r = 0; r < 4; ++r) {
        const int row = tileM + mi * 16 + quad * 4 + r;
        const long ci = (long)row * 256 + col;
        const float v = accO[mi][ni][r] + ld(b2, col, f) + ld(x, ci, f);
        if (f) ((float*)out)[ci] = v; else ((u16*)out)[ci] = f2b(v);
      }
    }
}

// ---------------------------------------------------------------------------
// K3: MFMA attention accumulation (unchanged).
__global__ __launch_bounds__(256) void attn_accum_kernel(
    const u16* __restrict__ qk, float* __restrict__ A_part, int pair0)
{
  const int pl = blockIdx.x;
  const int split = blockIdx.y;
  const int bl = pl >> 3, h = pl & 7;
  const int tid = threadIdx.x;
  const int wave = tid >> 6, lane = tid & 63;
  const int quad = lane >> 4, l16 = lane & 15;
  const int dq = wave >> 1, eq = wave & 1;
  __shared__ __align__(16) u16 lqT[32 * 72];
  __shared__ __align__(16) u16 lkT[32 * 72];
  const long rowbase = (long)bl * 3136 * 512;
  const int n0 = split * 448;
  f32x4 acc = (f32x4){0.f, 0.f, 0.f, 0.f};
  const int seg = tid & 7;

  for (int ch = 0; ch < 7; ++ch) {
    const int nb = n0 + ch * 64;
    #pragma unroll
    for (int rr = 0; rr < 2; ++rr) {
      const int a = rr * 256 + tid;
      const int nl = a >> 3;
      const int co = (seg < 4) ? h * 32 + seg * 8 : 256 + h * 32 + (seg - 4) * 8;
      const u16x8 v8 = *(const u16x8*)(qk + rowbase + (long)(nb + nl) * 512 + co);
      float vf[8], p = 0.f;
      #pragma unroll
      for (int i = 0; i < 8; ++i) { vf[i] = h2f(v8[i]); p += vf[i] * vf[i]; }
      float p1 = p + __shfl_xor(p, 1);
      float p2 = p1 + __shfl_xor(p1, 2);
      const float other = __shfl_xor(p2, 4);
      const float ssq = (seg < 4) ? p2 : other;
      const float ssk = (seg < 4) ? other : p2;
      const float s = 0.17677669529663687f * rsqrtf(fmaxf(ssq, 1e-12f)) *
                      rsqrtf(fmaxf(ssk, 1e-12f));
      if (seg < 4) {
        const int db = seg * 8;
        #pragma unroll
        for (int i = 0; i < 8; ++i) {
          const int d = db + i;
          lqT[d * 72 + (nl ^ (d & 24))] = f2h(vf[i] * s);
        }
      } else {
        const int eb = (seg - 4) * 8;
        #pragma unroll
        for (int i = 0; i < 8; ++i) {
          const int e = eb + i;
          lkT[e * 72 + (nl ^ (e & 24))] = v8[i];
        }
      }
    }
    __syncthreads();
    #pragma unroll
    for (int ks = 0; ks < 2; ++ks) {
      const int tb = ks * 32 + quad * 8;
      const int dA = dq * 16 + l16;
      const int eB = eq * 16 + l16;
      const f16x8 af = *(const f16x8*)&lqT[dA * 72 + (tb ^ (dA & 24))];
      const f16x8 bf = *(const f16x8*)&lkT[eB * 72 + (tb ^ (eB & 24))];
      acc = __builtin_amdgcn_mfma_f32_16x16x32_f16(af, bf, acc, 0, 0, 0);
    }
    __syncthreads();
  }
  float* o = A_part + ((long)(pair0 + pl) * SPLITN + split) * 1024;
  #pragma unroll
  for (int r = 0; r < 4; ++r)
    o[(dq * 16 + quad * 4 + r) * 32 + eq * 16 + l16] = acc[r];
}

__global__ __launch_bounds__(1024) void softmax_kernel(float* A_part) {
  const int pair = blockIdx.x;
  const int t = threadIdx.x;
  float v = 0.f;
  float* base = A_part + (long)pair * SPLITN * 1024 + t;
  #pragma unroll
  for (int s = 0; s < SPLITN; ++s) v += base[s * 1024];
  float mx = v;
  #pragma unroll
  for (int m = 16; m; m >>= 1) mx = fmaxf(mx, __shfl_xor(mx, m, 32));
  const float p = expf(v - mx);
  float sm = p;
  #pragma unroll
  for (int m = 16; m; m >>= 1) sm += __shfl_xor(sm, m, 32);
  base[0] = p / sm;
}

__global__ __launch_bounds__(256) void wb_kernel(
    const float* __restrict__ A_part, const void* __restrict__ proj_w,
    u16* __restrict__ Wbt, const int* __restrict__ flagp)
{
  const int f = *flagp;
  const int b = blockIdx.x;
  const int cs = blockIdx.y;
  const int tid = threadIdx.x;
  const int cg = tid & 31, dg = tid >> 5;
  const int c = cs * 32 + cg;
  __shared__ float Ah[32][32];
  __shared__ float pw[32][33];
  for (int h = 0; h < 8; ++h) {
    const float* Abase = A_part + ((long)(b * 8 + h) * SPLITN) * 1024;
    #pragma unroll
    for (int rr = 0; rr < 4; ++rr) {
      const int ff = rr * 256 + tid;
      Ah[ff >> 5][ff & 31] = Abase[ff];
    }
    #pragma unroll
    for (int rr = 0; rr < 4; ++rr) {
      const int ff = rr * 256 + tid;
      const int e = ff >> 5, ccc = ff & 31;
      pw[e][ccc] = ld(proj_w, (long)(h * 32 + e) * 256 + cs * 32 + ccc, f);
    }
    __syncthreads();
    float acc[4] = {0.f, 0.f, 0.f, 0.f};
    #pragma unroll
    for (int e = 0; e < 32; ++e) {
      const float pv = pw[e][cg];
      #pragma unroll
      for (int dd = 0; dd < 4; ++dd)
        acc[dd] += Ah[dg * 4 + dd][e] * pv;
    }
    #pragma unroll
    for (int dd = 0; dd < 4; ++dd)
      Wbt[((long)b * 256 + c) * 256 + h * 32 + dg * 4 + dd] = f2h(acc[dd]);
    __syncthreads();
  }
}

extern "C" void kernel_launch(void* const* d_in, const int* in_sizes, int n_in,
                              void* d_out, int out_size, void* d_ws, size_t ws_size,
                              hipStream_t stream) {
  const void* x      = d_in[0];
  const void* dwk    = d_in[1];
  const void* dwb    = d_in[2];
  const void* lng    = d_in[3];
  const void* lnb    = d_in[4];
  const void* qkv_w  = d_in[5];
  const void* proj_w = d_in[6];
  const void* proj_b = d_in[7];
  const void* bn_g   = d_in[8];
  const void* bn_b   = d_in[9];
  const void* bn_m   = d_in[10];
  const void* bn_v   = d_in[11];
  const void* fc1_w  = d_in[12];
  const void* fc1_b  = d_in[13];
  const void* fc2_w  = d_in[14];
  const void* fc2_b  = d_in[15];
  char* ws = (char*)d_ws;

  int*   flagp   = (int*)  (ws + 0);
  u16*   wqkvT   = (u16*)  (ws + 256);
  u16*   wfc1T   = (u16*)  (ws + 393472);
  u16*   wfc2T   = (u16*)  (ws + 917760);
  float* A_part  = (float*)(ws + 1442048);
  u16*   Wbt     = (u16*)  (ws + 5112064);
  u16*   vbuf    = (u16*)  (ws + 7209216);
  u16*   dwc     = (u16*)  (ws + 32899328);
  u16*   qk_half = (u16*)  (ws + 58589440);
  u16*   norm1   = (u16*)d_out;  // fp16-bit scratch; dead before mlp writes out

  detect_kernel<<<1, 256, 0, stream>>>((const u16*)x, flagp);

  transpose_cvt_kernel<<<2816, 256, 0, stream>>>(qkv_w, wqkvT, fc1_w, wfc1T,
                                                 fc2_w, wfc2T, flagp);

  dwconv_ln_kernel<<<3136, 256, 0, stream>>>(x, dwk, dwb, lng, lnb, dwc, norm1, flagp);

  for (int half = 0; half < 2; ++half) {
    const u16* nh = norm1 + (long)half * 25088 * 256;
    gemm_kernel<128, 2, 2, 5, 256><<<dim3(6, 196, 1), 256, 0, stream>>>(
        nh, wqkvT, qk_half, 256, 256, 512, 0, 0, 0, (long)half * 25088 * 256,
        nullptr, vbuf, nullptr, nullptr, nullptr, nullptr, flagp);
    attn_accum_kernel<<<dim3(64, SPLITN), 256, 0, stream>>>(qk_half, A_part, half * 64);
  }

  softmax_kernel<<<128, 1024, 0, stream>>>(A_part);
  wb_kernel<<<dim3(16, 8), 256, 0, stream>>>(A_part, proj_w, Wbt, flagp);

  // merged = BN( V @ W_b + proj_b + dwconv ) — in-place into dwc
  gemm_kernel<64, 1, 4, 2, 256><<<dim3(2, 49, 16), 256, 0, stream>>>(
      vbuf, Wbt, dwc, 256, 256, 256,
      (long)3136 * 256, 65536, (long)3136 * 256, 0,
      proj_b, dwc, bn_g, bn_b, bn_m, bn_v, flagp);

  // fused MLP: out = x + gelu(merged @ W1 + b1) @ W2 + b2
  mlp_kernel<<<784, 256, 0, stream>>>(dwc, wfc1T, wfc2T, fc1_b, fc2_b, x, d_out, flagp);
}